// Round 1
// baseline (14702.905 us; speedup 1.0000x reference)
//
#include <hip/hip_runtime.h>
#include <math.h>

// Problem constants
// B=4, C=4, D=96, NS=12, HIN=128, PZ=32, TOTAL_Z=64, window 4x4x4 (64 tok), NH=3, dh=32

// ---------------- tables: searchsorted interp (z64 from pos, z32 from pos/2) ----------------
// T layout (ints): [0..63] l64, [64..127] r64, [128..191] w64(float), [192..223] l32, [224..255] r32, [256..287] w32(float)
__global__ __launch_bounds__(96) void k_tables(const int* __restrict__ sidx, int* __restrict__ T) {
  __shared__ float pos[12];
  int t = threadIdx.x;
  if (t < 12) pos[t] = (float)sidx[t];
  __syncthreads();
  if (t < 64) {
    float zq = (float)t;
    int r = 0;
    while (r < 12 && pos[r] < zq) r++;
    int l = r - 1; if (l < 0) l = 0; if (l > 11) l = 11;
    int rc = r; if (rc > 11) rc = 11;
    float lp = pos[l], rp = pos[rc], d = rp - lp;
    float w = d > 0.f ? (zq - lp) / d : 0.5f;
    T[t] = l; T[64 + t] = rc; ((float*)T)[128 + t] = w;
  } else {
    int zq = t - 64;
    float zqf = (float)zq;
    int r = 0;
    while (r < 12 && pos[r] * 0.5f < zqf) r++;
    int l = r - 1; if (l < 0) l = 0; if (l > 11) l = 11;
    int rc = r; if (rc > 11) rc = 11;
    float lp = pos[l] * 0.5f, rp = pos[rc] * 0.5f, d = rp - lp;
    float w = d > 0.f ? (zqf - lp) / d : 0.5f;
    T[192 + zq] = l; T[224 + zq] = rc; ((float*)T)[256 + zq] = w;
  }
}

// ---------------- patch embed (4x4, C=4 -> D=96) + LayerNorm over D ----------------
// grid: b*12*32 (one block per (b,z,h) output row), 256 threads
__global__ __launch_bounds__(256) void k_pe(const float* __restrict__ sp, const float* __restrict__ pw,
    const float* __restrict__ pb, const float* __restrict__ pg, const float* __restrict__ pbeta,
    float* __restrict__ f1) {
  int x = blockIdx.x;
  int b = x / 384, z = (x / 32) % 12, h = x % 32;
  __shared__ float sIn[4][4][128];   // c,p,col
  __shared__ float sF[32][97];       // w,d (pad 97)
  __shared__ float sM[32], sR[32];
  int tid = threadIdx.x;
  for (int id = tid; id < 2048; id += 256) {
    int c = id >> 9, p = (id >> 7) & 3, col = id & 127;
    sIn[c][p][col] = sp[(((b * 4 + c) * 12 + z) * 128 + h * 4 + p) * 128 + col];
  }
  __syncthreads();
  for (int id = tid; id < 3072; id += 256) {
    int w = id / 96, d = id % 96;
    float acc = pb[d];
    #pragma unroll
    for (int c = 0; c < 4; c++)
      #pragma unroll
      for (int p = 0; p < 4; p++)
        #pragma unroll
        for (int q = 0; q < 4; q++)
          acc += sIn[c][p][w * 4 + q] * pw[((d * 4 + c) * 4 + p) * 4 + q];
    sF[w][d] = acc;
  }
  __syncthreads();
  if (tid < 32) {
    int w = tid;
    float s = 0.f, ss = 0.f;
    for (int d = 0; d < 96; d++) { float v = sF[w][d]; s += v; ss += v * v; }
    float m = s * (1.f / 96.f);
    float var = ss * (1.f / 96.f) - m * m;
    sM[w] = m; sR[w] = rsqrtf(var + 1e-5f);
  }
  __syncthreads();
  for (int id = tid; id < 3072; id += 256) {
    int d = id >> 5, w = id & 31;
    float v = (sF[w][d] - sM[w]) * sR[w] * pg[d] + pbeta[d];
    f1[(((b * 96 + d) * 12 + z) * 32 + h) * 32 + w] = v;
  }
}

// ---------------- z-interp 12->32 + encoder projection (96x96) fused ----------------
// grid: b*512 (64 voxels per block), 256 threads
__global__ __launch_bounds__(256) void k_ie(const float* __restrict__ f1, const float* __restrict__ ef,
    const float* __restrict__ ew, const float* __restrict__ eb, const int* __restrict__ T,
    float* __restrict__ f2) {
  int x = blockIdx.x;
  int b = x >> 9, chunk = x & 511;
  int v0 = chunk * 64;
  int z = v0 >> 10, rp = v0 & 1023;
  int zl = T[192 + z], zr = T[224 + z];
  float wt = ((const float*)T)[256 + z];
  __shared__ float sE[96][64];
  int tid = threadIdx.x;
  for (int id = tid; id < 6144; id += 256) {
    int c = id >> 6, vs = id & 63;
    sE[c][vs] = ef[(b * 96 + c) * 32768 + v0 + vs];
  }
  __syncthreads();
  for (int id = tid; id < 6144; id += 256) {
    int d = id >> 6, vs = id & 63;
    float acc = eb[d];
    for (int c = 0; c < 96; c++) acc += sE[c][vs] * ew[d * 96 + c];
    const float* p1 = f1 + ((size_t)(b * 96 + d) * 12 + zl) * 1024 + rp + vs;
    const float* p2 = f1 + ((size_t)(b * 96 + d) * 12 + zr) * 1024 + rp + vs;
    f2[(size_t)(b * 96 + d) * 32768 + v0 + vs] = (1.f - wt) * p1[0] + wt * p2[0] + acc;
  }
}

// ---------------- Swin window attention: one block per 4x4x4 window ----------------
__global__ __launch_bounds__(256) void k_attn(const float* __restrict__ f2,
    const float* __restrict__ lg, const float* __restrict__ lb,
    const float* __restrict__ qw, const float* __restrict__ qb,
    const float* __restrict__ aw, const float* __restrict__ ab,
    const float* __restrict__ rpb, float* __restrict__ f3) {
  int wi = blockIdx.x;
  int b = wi >> 9, zb = (wi >> 6) & 7, hb = (wi >> 3) & 7, wb = wi & 7;
  __shared__ float sX[64][97];  // raw x (residual)
  __shared__ float sN[64][97];  // normalized
  __shared__ float sO[64][97];  // attention out (all heads)
  __shared__ float sQ[64][33], sK[64][33], sV[64][33];
  __shared__ float sS[64][65];
  int tid = threadIdx.x;
  for (int id = tid; id < 6144; id += 256) {
    int d = id >> 6, t = id & 63;
    int tz = t >> 4, th = (t >> 2) & 3, tw = t & 3;
    sX[t][d] = f2[(((b * 96 + d) * 32 + zb * 4 + tz) * 32 + hb * 4 + th) * 32 + wb * 4 + tw];
  }
  __syncthreads();
  if (tid < 64) {
    int t = tid;
    float s = 0.f, ss = 0.f;
    for (int d = 0; d < 96; d++) { float v = sX[t][d]; s += v; ss += v * v; }
    float m = s * (1.f / 96.f);
    float r = rsqrtf(ss * (1.f / 96.f) - m * m + 1e-5f);
    for (int d = 0; d < 96; d++) sN[t][d] = (sX[t][d] - m) * r * lg[d] + lb[d];
  }
  __syncthreads();
  const float scale = 0.17677669529663687f; // 1/sqrt(32)
  for (int head = 0; head < 3; head++) {
    for (int id = tid; id < 2048; id += 256) {
      int t = id >> 5, c = id & 31;
      int row = head * 32 + c;
      float a0 = qb[row], a1 = qb[96 + row], a2 = qb[192 + row];
      for (int d = 0; d < 96; d++) {
        float xv = sN[t][d];
        a0 += xv * qw[row * 96 + d];
        a1 += xv * qw[(96 + row) * 96 + d];
        a2 += xv * qw[(192 + row) * 96 + d];
      }
      sQ[t][c] = a0 * scale; sK[t][c] = a1; sV[t][c] = a2;
    }
    __syncthreads();
    for (int id = tid; id < 4096; id += 256) {
      int n = id >> 6, m = id & 63;
      int dz = (n >> 4) - (m >> 4), dh = ((n >> 2) & 3) - ((m >> 2) & 3), dw = (n & 3) - (m & 3);
      float acc = rpb[((dz + 3) * 49 + (dh + 3) * 7 + (dw + 3)) * 3 + head];
      for (int c = 0; c < 32; c++) acc += sQ[n][c] * sK[m][c];
      sS[n][m] = acc;
    }
    __syncthreads();
    if (tid < 64) {
      int n = tid;
      float mx = -1e30f;
      for (int m = 0; m < 64; m++) mx = fmaxf(mx, sS[n][m]);
      float s = 0.f;
      for (int m = 0; m < 64; m++) { float e = __expf(sS[n][m] - mx); sS[n][m] = e; s += e; }
      float inv = 1.f / s;
      for (int m = 0; m < 64; m++) sS[n][m] *= inv;
    }
    __syncthreads();
    for (int id = tid; id < 2048; id += 256) {
      int n = id >> 5, c = id & 31;
      float acc = 0.f;
      for (int m = 0; m < 64; m++) acc += sS[n][m] * sV[m][c];
      sO[n][head * 32 + c] = acc;
    }
    __syncthreads();
  }
  for (int id = tid; id < 6144; id += 256) {
    int d = id >> 6, t = id & 63;
    float acc = ab[d] + sX[t][d];
    for (int e = 0; e < 96; e++) acc += sO[t][e] * aw[d * 96 + e];
    int tz = t >> 4, th = (t >> 2) & 3, tw = t & 3;
    f3[(((b * 96 + d) * 32 + zb * 4 + tz) * 32 + hb * 4 + th) * 32 + wb * 4 + tw] = acc;
  }
}

// ---------------- 3x3x3 conv (96->96, pad 1) + per-(b,group) sum/sumsq atomics ----------------
// grid: b*96*32*4 ; block 256 = (w 32, h 8)
__global__ __launch_bounds__(256) void k_conv(const float* __restrict__ in,
    const float* __restrict__ wc, const float* __restrict__ cb,
    float* __restrict__ out, float* __restrict__ stats) {
  int x = blockIdx.x;
  int b = x / 12288; int rem = x % 12288;
  int o = rem / 128; int rem2 = rem % 128;
  int z = rem2 >> 2, ht = rem2 & 3;
  int tid = threadIdx.x;
  int w = tid & 31, h = ht * 8 + (tid >> 5);
  float acc = cb[o];
  const float* ip = in + (size_t)(b * 96) * 32768;
  const float* wp = wc + (size_t)o * 96 * 27;
  for (int i = 0; i < 96; i++) {
    #pragma unroll
    for (int dz = 0; dz < 3; dz++) {
      int zz = z + dz - 1;
      if (zz < 0 || zz > 31) continue;
      #pragma unroll
      for (int dh = 0; dh < 3; dh++) {
        int hh = h + dh - 1;
        if (hh < 0 || hh > 31) continue;
        #pragma unroll
        for (int dw = 0; dw < 3; dw++) {
          int ww = w + dw - 1;
          float xv = (ww >= 0 && ww <= 31) ? ip[(size_t)i * 32768 + (zz * 32 + hh) * 32 + ww] : 0.f;
          acc += xv * wp[i * 27 + dz * 9 + dh * 3 + dw];
        }
      }
    }
  }
  out[(((size_t)(b * 96 + o) * 32 + z) * 32 + h) * 32 + w] = acc;
  __shared__ float rs[256], rss[256];
  rs[tid] = acc; rss[tid] = acc * acc;
  __syncthreads();
  for (int s = 128; s > 0; s >>= 1) {
    if (tid < s) { rs[tid] += rs[tid + s]; rss[tid] += rss[tid + s]; }
    __syncthreads();
  }
  if (tid == 0) {
    int g = b * 8 + o / 12;
    atomicAdd(&stats[g * 2], rs[0]);
    atomicAdd(&stats[g * 2 + 1], rss[0]);
  }
}

// ---------------- GroupNorm apply + exact GELU ----------------
__global__ __launch_bounds__(256) void k_gn(const float* __restrict__ y, const float* __restrict__ stats,
    const float* __restrict__ gg, const float* __restrict__ gb, float* __restrict__ out) {
  size_t idx = (size_t)blockIdx.x * 256 + threadIdx.x;
  int b = (int)(idx / 3145728);
  int d = (int)((idx >> 15) % 96);
  int g = b * 8 + d / 12;
  float s1 = stats[g * 2], s2 = stats[g * 2 + 1];
  const float invN = 1.f / 393216.f;
  float m = s1 * invN;
  float var = s2 * invN - m * m;
  float v = (y[idx] - m) * rsqrtf(var + 1e-5f) * gg[d] + gb[d];
  out[idx] = 0.5f * v * (1.f + erff(v * 0.70710678118654752f));
}

// ---------------- reconstruct (96 -> 4 x (2,4,4) upsample) + baseline z-interp, write output ----------------
// grid: b*1024 (one block per (b,z,h) row = 32 voxels), 256 threads
__global__ __launch_bounds__(256) void k_final(const float* __restrict__ f5, const float* __restrict__ sp,
    const float* __restrict__ rw, const float* __restrict__ rb, const int* __restrict__ T,
    float* __restrict__ out) {
  int x = blockIdx.x;
  int b = x >> 10, chunk = x & 1023;
  int z = chunk >> 5, h = chunk & 31;
  int v0 = chunk * 32;
  __shared__ float sF[96][32];
  int tid = threadIdx.x;
  for (int id = tid; id < 3072; id += 256) {
    int i = id >> 5, wv = id & 31;
    sF[i][wv] = f5[(size_t)(b * 96 + i) * 32768 + v0 + wv];
  }
  __syncthreads();
  const float* w64 = (const float*)(T + 128);
  for (int it = 0; it < 16; it++) {
    int id = tid + 256 * it;
    int wv = id >> 7, j = id & 127;
    int o = j >> 5, dd = (j >> 4) & 1, e = (j >> 2) & 3, ff = j & 3;
    float acc = 0.f;
    for (int i = 0; i < 96; i++) acc += sF[i][wv] * rw[i * 128 + j];
    int Z = 2 * z + dd, H = 4 * h + e, W = 4 * wv + ff;
    int zl = T[Z], zr = T[64 + Z];
    float bw = w64[Z];
    const float* spb = sp + (size_t)(b * 4 + o) * 12 * 16384;
    float bval = (1.f - bw) * spb[(size_t)zl * 16384 + H * 128 + W]
               + bw * spb[(size_t)zr * 16384 + H * 128 + W];
    out[((size_t)(b * 4 + o) * 64 + Z) * 16384 + H * 128 + W] = bval + acc + rb[o];
  }
}

extern "C" void kernel_launch(void* const* d_in, const int* in_sizes, int n_in,
                              void* d_out, int out_size, void* d_ws, size_t ws_size,
                              hipStream_t stream) {
  const float* sp    = (const float*)d_in[0];
  const float* ef    = (const float*)d_in[1];
  const float* pe_w  = (const float*)d_in[2];
  const float* pe_b  = (const float*)d_in[3];
  const float* pe_g  = (const float*)d_in[4];
  const float* pe_be = (const float*)d_in[5];
  const float* enc_w = (const float*)d_in[6];
  const float* enc_b = (const float*)d_in[7];
  const float* ln_g  = (const float*)d_in[8];
  const float* ln_b  = (const float*)d_in[9];
  const float* qkv_w = (const float*)d_in[10];
  const float* qkv_b = (const float*)d_in[11];
  const float* at_w  = (const float*)d_in[12];
  const float* at_b  = (const float*)d_in[13];
  const float* rpb   = (const float*)d_in[14];
  const float* w1    = (const float*)d_in[15];
  const float* b1    = (const float*)d_in[16];
  const float* g1g   = (const float*)d_in[17];
  const float* g1b   = (const float*)d_in[18];
  const float* w2    = (const float*)d_in[19];
  const float* b2    = (const float*)d_in[20];
  const float* g2g   = (const float*)d_in[21];
  const float* g2b   = (const float*)d_in[22];
  const float* recw  = (const float*)d_in[23];
  const float* recb  = (const float*)d_in[24];
  const int*   sidx  = (const int*)d_in[25];
  float* out = (float*)d_out;

  char* ws = (char*)d_ws;
  const size_t BIG = 50331648; // 4*96*32768*4 bytes
  float* A  = (float*)ws;              // f2, then y1, then y2
  float* Bf = (float*)(ws + BIG);      // f1, then f4, then f5
  int*   T  = (int*)(ws + 2 * BIG);    // interp tables (~1.2KB)
  float* stats = (float*)(ws + 2 * BIG + 4096); // 64 floats

  k_tables<<<1, 96, 0, stream>>>(sidx, T);
  k_pe<<<1536, 256, 0, stream>>>(sp, pe_w, pe_b, pe_g, pe_be, Bf);
  k_ie<<<2048, 256, 0, stream>>>(Bf, ef, enc_w, enc_b, T, A);
  k_attn<<<2048, 256, 0, stream>>>(A, ln_g, ln_b, qkv_w, qkv_b, at_w, at_b, rpb, out);

  hipMemsetAsync(stats, 0, 64 * sizeof(float), stream);
  k_conv<<<49152, 256, 0, stream>>>(out, w1, b1, A, stats);
  k_gn<<<49152, 256, 0, stream>>>(A, stats, g1g, g1b, Bf);

  hipMemsetAsync(stats, 0, 64 * sizeof(float), stream);
  k_conv<<<49152, 256, 0, stream>>>(Bf, w2, b2, A, stats);
  k_gn<<<49152, 256, 0, stream>>>(A, stats, g2g, g2b, Bf);

  k_final<<<4096, 256, 0, stream>>>(Bf, sp, recw, recb, T, out);
}

// Round 2
// 3383.289 us; speedup vs baseline: 4.3457x; 4.3457x over previous
//
#include <hip/hip_runtime.h>
#include <math.h>

typedef __attribute__((ext_vector_type(8))) short short8v;
typedef __attribute__((ext_vector_type(4))) float float4v;

__device__ inline unsigned short f2bf(float f) {
  unsigned u = __float_as_uint(f);
  return (unsigned short)((u + 0x7fff + ((u >> 16) & 1)) >> 16);
}
__device__ inline float bfl(unsigned u) { return __uint_as_float(u << 16); }
__device__ inline float bfh(unsigned u) { return __uint_as_float(u & 0xffff0000u); }

// ---------------- tables ----------------
__global__ __launch_bounds__(96) void k_tables(const int* __restrict__ sidx, int* __restrict__ T) {
  __shared__ float pos[12];
  int t = threadIdx.x;
  if (t < 12) pos[t] = (float)sidx[t];
  __syncthreads();
  if (t < 64) {
    float zq = (float)t;
    int r = 0;
    while (r < 12 && pos[r] < zq) r++;
    int l = r - 1; if (l < 0) l = 0; if (l > 11) l = 11;
    int rc = r; if (rc > 11) rc = 11;
    float lp = pos[l], rp = pos[rc], d = rp - lp;
    float w = d > 0.f ? (zq - lp) / d : 0.5f;
    T[t] = l; T[64 + t] = rc; ((float*)T)[128 + t] = w;
  } else {
    int zq = t - 64;
    float zqf = (float)zq;
    int r = 0;
    while (r < 12 && pos[r] * 0.5f < zqf) r++;
    int l = r - 1; if (l < 0) l = 0; if (l > 11) l = 11;
    int rc = r; if (rc > 11) rc = 11;
    float lp = pos[l] * 0.5f, rp = pos[rc] * 0.5f, d = rp - lp;
    float w = d > 0.f ? (zqf - lp) / d : 0.5f;
    T[192 + zq] = l; T[224 + zq] = rc; ((float*)T)[256 + zq] = w;
  }
}

// ---------------- weight convert: [o][i][27] f32 -> [tap][o][i] bf16 ----------------
__global__ __launch_bounds__(256) void k_wcv(const float* __restrict__ w, short* __restrict__ Wt) {
  int id = blockIdx.x * 256 + threadIdx.x;
  if (id >= 248832) return;
  float v = w[id];
  int o = id / 2592; int rem = id % 2592; int i = rem / 27; int tap = rem % 27;
  Wt[(tap * 96 + o) * 96 + i] = (short)f2bf(v);
}

// ---------------- patch embed + LayerNorm ----------------
__global__ __launch_bounds__(256) void k_pe(const float* __restrict__ sp, const float* __restrict__ pw,
    const float* __restrict__ pb, const float* __restrict__ pg, const float* __restrict__ pbeta,
    float* __restrict__ f1) {
  int x = blockIdx.x;
  int b = x / 384, z = (x / 32) % 12, h = x % 32;
  __shared__ float sIn[4][4][128];
  __shared__ float sF[32][97];
  __shared__ float sM[32], sR[32];
  int tid = threadIdx.x;
  for (int id = tid; id < 2048; id += 256) {
    int c = id >> 9, p = (id >> 7) & 3, col = id & 127;
    sIn[c][p][col] = sp[(((b * 4 + c) * 12 + z) * 128 + h * 4 + p) * 128 + col];
  }
  __syncthreads();
  for (int id = tid; id < 3072; id += 256) {
    int w = id / 96, d = id % 96;
    float acc = pb[d];
    #pragma unroll
    for (int c = 0; c < 4; c++)
      #pragma unroll
      for (int p = 0; p < 4; p++)
        #pragma unroll
        for (int q = 0; q < 4; q++)
          acc += sIn[c][p][w * 4 + q] * pw[((d * 4 + c) * 4 + p) * 4 + q];
    sF[w][d] = acc;
  }
  __syncthreads();
  if (tid < 32) {
    int w = tid;
    float s = 0.f, ss = 0.f;
    for (int d = 0; d < 96; d++) { float v = sF[w][d]; s += v; ss += v * v; }
    float m = s * (1.f / 96.f);
    float var = ss * (1.f / 96.f) - m * m;
    sM[w] = m; sR[w] = rsqrtf(var + 1e-5f);
  }
  __syncthreads();
  for (int id = tid; id < 3072; id += 256) {
    int d = id >> 5, w = id & 31;
    float v = (sF[w][d] - sM[w]) * sR[w] * pg[d] + pbeta[d];
    f1[(((b * 96 + d) * 12 + z) * 32 + h) * 32 + w] = v;
  }
}

// ---------------- z-interp 12->32 + encoder projection ----------------
__global__ __launch_bounds__(256) void k_ie(const float* __restrict__ f1, const float* __restrict__ ef,
    const float* __restrict__ ew, const float* __restrict__ eb, const int* __restrict__ T,
    float* __restrict__ f2) {
  int x = blockIdx.x;
  int b = x >> 9, chunk = x & 511;
  int v0 = chunk * 64;
  int z = v0 >> 10, rp = v0 & 1023;
  int zl = T[192 + z], zr = T[224 + z];
  float wt = ((const float*)T)[256 + z];
  __shared__ float sE[96][64];
  int tid = threadIdx.x;
  for (int id = tid; id < 6144; id += 256) {
    int c = id >> 6, vs = id & 63;
    sE[c][vs] = ef[(b * 96 + c) * 32768 + v0 + vs];
  }
  __syncthreads();
  for (int id = tid; id < 6144; id += 256) {
    int d = id >> 6, vs = id & 63;
    float acc = eb[d];
    for (int c = 0; c < 96; c++) acc += sE[c][vs] * ew[d * 96 + c];
    const float* p1 = f1 + ((size_t)(b * 96 + d) * 12 + zl) * 1024 + rp + vs;
    const float* p2 = f1 + ((size_t)(b * 96 + d) * 12 + zr) * 1024 + rp + vs;
    f2[(size_t)(b * 96 + d) * 32768 + v0 + vs] = (1.f - wt) * p1[0] + wt * p2[0] + acc;
  }
}

// ---------------- Swin window attention -> bf16 transposed output [b][c][vox][i32] ----------------
__global__ __launch_bounds__(256) void k_attn(const float* __restrict__ f2,
    const float* __restrict__ lg, const float* __restrict__ lb,
    const float* __restrict__ qw, const float* __restrict__ qb,
    const float* __restrict__ aw, const float* __restrict__ ab,
    const float* __restrict__ rpb, short* __restrict__ xt) {
  int wi = blockIdx.x;
  int b = wi >> 9, zb = (wi >> 6) & 7, hb = (wi >> 3) & 7, wb = wi & 7;
  __shared__ float sX[64][97];
  __shared__ float sN[64][97];
  __shared__ float sO[64][97];
  __shared__ float sQ[64][33], sK[64][33], sV[64][33];
  __shared__ float sS[64][65];
  int tid = threadIdx.x;
  for (int id = tid; id < 6144; id += 256) {
    int d = id >> 6, t = id & 63;
    int tz = t >> 4, th = (t >> 2) & 3, tw = t & 3;
    sX[t][d] = f2[(((b * 96 + d) * 32 + zb * 4 + tz) * 32 + hb * 4 + th) * 32 + wb * 4 + tw];
  }
  __syncthreads();
  if (tid < 64) {
    int t = tid;
    float s = 0.f, ss = 0.f;
    for (int d = 0; d < 96; d++) { float v = sX[t][d]; s += v; ss += v * v; }
    float m = s * (1.f / 96.f);
    float r = rsqrtf(ss * (1.f / 96.f) - m * m + 1e-5f);
    for (int d = 0; d < 96; d++) sN[t][d] = (sX[t][d] - m) * r * lg[d] + lb[d];
  }
  __syncthreads();
  const float scale = 0.17677669529663687f;
  for (int head = 0; head < 3; head++) {
    for (int id = tid; id < 2048; id += 256) {
      int t = id >> 5, c = id & 31;
      int row = head * 32 + c;
      float a0 = qb[row], a1 = qb[96 + row], a2 = qb[192 + row];
      for (int d = 0; d < 96; d++) {
        float xv = sN[t][d];
        a0 += xv * qw[row * 96 + d];
        a1 += xv * qw[(96 + row) * 96 + d];
        a2 += xv * qw[(192 + row) * 96 + d];
      }
      sQ[t][c] = a0 * scale; sK[t][c] = a1; sV[t][c] = a2;
    }
    __syncthreads();
    for (int id = tid; id < 4096; id += 256) {
      int n = id >> 6, m = id & 63;
      int dz = (n >> 4) - (m >> 4), dh = ((n >> 2) & 3) - ((m >> 2) & 3), dw = (n & 3) - (m & 3);
      float acc = rpb[((dz + 3) * 49 + (dh + 3) * 7 + (dw + 3)) * 3 + head];
      for (int c = 0; c < 32; c++) acc += sQ[n][c] * sK[m][c];
      sS[n][m] = acc;
    }
    __syncthreads();
    if (tid < 64) {
      int n = tid;
      float mx = -1e30f;
      for (int m = 0; m < 64; m++) mx = fmaxf(mx, sS[n][m]);
      float s = 0.f;
      for (int m = 0; m < 64; m++) { float e = __expf(sS[n][m] - mx); sS[n][m] = e; s += e; }
      float inv = 1.f / s;
      for (int m = 0; m < 64; m++) sS[n][m] *= inv;
    }
    __syncthreads();
    for (int id = tid; id < 2048; id += 256) {
      int n = id >> 5, c = id & 31;
      float acc = 0.f;
      for (int m = 0; m < 64; m++) acc += sS[n][m] * sV[m][c];
      sO[n][head * 32 + c] = acc;
    }
    __syncthreads();
  }
  // epilogue: residual + proj, write bf16 transposed
  for (int id = tid; id < 3072; id += 256) {
    int row = id >> 6;           // c(3) tz(4) th(4)
    int colp = id & 63;          // tw(4) x ilp(16)
    int tw = colp >> 4, ilp = colp & 15;
    int cc = row >> 4, tz = (row >> 2) & 3, th = row & 3;
    int t = tz * 16 + th * 4 + tw;
    int d0 = cc * 32 + ilp * 2, d1 = d0 + 1;
    float a0 = ab[d0] + sX[t][d0], a1 = ab[d1] + sX[t][d1];
    for (int e = 0; e < 96; e++) {
      float ov = sO[t][e];
      a0 += ov * aw[d0 * 96 + e];
      a1 += ov * aw[d1 * 96 + e];
    }
    unsigned pk = (unsigned)f2bf(a0) | ((unsigned)f2bf(a1) << 16);
    size_t vox = ((size_t)(zb * 4 + tz) << 10) + ((hb * 4 + th) << 5) + wb * 4 + tw;
    ((unsigned*)xt)[((size_t)(b * 3 + cc) * 32768 + vox) * 16 + ilp] = pk;
  }
}

// ---------------- MFMA conv 3x3x3: in bf16 [b][c][vox][i32], W bf16 [tap][o][i96] -> y f32 [b][o][vox]
__global__ __launch_bounds__(512) void k_convM(const short* __restrict__ Xt,
    const short* __restrict__ Wt, const float* __restrict__ cb, float* __restrict__ y) {
  int x = blockIdx.x;
  int b = x >> 7, z = (x >> 2) & 31, hq = x & 3;
  int tid = threadIdx.x;
  int wv = tid >> 6, l = tid & 63;
  int lo = l & 15, ig = l >> 4;
  __shared__ short Xl[32640];   // [3z][10h][34w][32i]
  float4v acc[6][2];
  #pragma unroll
  for (int m = 0; m < 6; m++)
    #pragma unroll
    for (int n = 0; n < 2; n++) acc[m][n] = (float4v){0.f, 0.f, 0.f, 0.f};

  for (int c = 0; c < 3; c++) {
    __syncthreads();
    // stage [z-1..z+1][hq*8-1..+8][w-1..32][i32] with zero pad
    for (int r = 0; r < 8; r++) {
      int id = tid + 512 * r;
      if (id < 4080) {
        int seg = id & 3, q = id >> 2;
        int zz = q / 340, rem = q - zz * 340;
        int hh = rem / 34, ww = rem - hh * 34;
        int gz = z + zz - 1, gh = hq * 8 + hh - 1, gw = ww - 1;
        int4 val = {0, 0, 0, 0};
        if (gz >= 0 && gz < 32 && gh >= 0 && gh < 32 && gw >= 0 && gw < 32)
          val = *(const int4*)(Xt + ((size_t)((b * 3 + c) * 32768 + (gz << 10) + (gh << 5) + gw) * 32 + seg * 8));
        *(int4*)(&Xl[q * 32 + seg * 8]) = val;
      }
    }
    __syncthreads();
    for (int tap = 0; tap < 27; tap++) {
      int dz = tap / 9, dh = (tap % 9) / 3, dwv = tap % 3;
      short8v a[6];
      #pragma unroll
      for (int m = 0; m < 6; m++)
        a[m] = *reinterpret_cast<const short8v*>(Wt + ((size_t)(tap * 96 + m * 16 + lo)) * 96 + c * 32 + ig * 8);
      #pragma unroll
      for (int n = 0; n < 2; n++) {
        int baddr = ((dz * 10 + wv + dh) * 34 + n * 16 + lo + dwv) * 32 + ig * 8;
        short8v bf = *reinterpret_cast<const short8v*>(&Xl[baddr]);
        #pragma unroll
        for (int m = 0; m < 6; m++)
          acc[m][n] = __builtin_amdgcn_mfma_f32_16x16x32_bf16(a[m], bf, acc[m][n], 0, 0, 0);
      }
    }
  }
  int h = hq * 8 + wv;
  #pragma unroll
  for (int m = 0; m < 6; m++)
    #pragma unroll
    for (int n = 0; n < 2; n++)
      #pragma unroll
      for (int r = 0; r < 4; r++) {
        int o = m * 16 + ig * 4 + r;
        int vcol = n * 16 + lo;
        y[((size_t)(b * 96 + o) << 15) + (z << 10) + (h << 5) + vcol] = acc[m][n][r] + cb[o];
      }
}

// ---------------- GN stats: sum/sumsq per (b,group) ----------------
__global__ __launch_bounds__(256) void k_stats(const float* __restrict__ y, float* __restrict__ stats) {
  int x = blockIdx.x;
  int bo = x >> 4, seg = x & 15;
  int b = bo / 96, o = bo % 96;
  const float* p = y + (size_t)bo * 32768 + seg * 2048;
  int tid = threadIdx.x;
  float s = 0.f, ss = 0.f;
  #pragma unroll
  for (int r = 0; r < 2; r++) {
    float4 v = ((const float4*)p)[tid + 256 * r];
    s += v.x + v.y + v.z + v.w;
    ss += v.x * v.x + v.y * v.y + v.z * v.z + v.w * v.w;
  }
  __shared__ float rs[256], rss[256];
  rs[tid] = s; rss[tid] = ss;
  __syncthreads();
  for (int st = 128; st > 0; st >>= 1) {
    if (tid < st) { rs[tid] += rs[tid + st]; rss[tid] += rss[tid + st]; }
    __syncthreads();
  }
  if (tid == 0) {
    int g = b * 8 + o / 12;
    atomicAdd(&stats[2 * g], rs[0]);
    atomicAdd(&stats[2 * g + 1], rss[0]);
  }
}

// ---------------- GN apply + GELU -> bf16 transposed [b][c][vox][i32] ----------------
__global__ __launch_bounds__(256) void k_gn(const float* __restrict__ y, const float* __restrict__ stats,
    const float* __restrict__ gg, const float* __restrict__ gb, short* __restrict__ xt) {
  int x = blockIdx.x;
  int b = x / 1536, r = x % 1536, c = r / 512, vt = r % 512;
  int v0 = vt * 64;
  __shared__ float sT[64][33];
  int tid = threadIdx.x;
  const float invN = 1.f / 393216.f;
  for (int id = tid; id < 2048; id += 256) {
    int ol = id >> 6, v = id & 63;
    int o = c * 32 + ol, g = b * 8 + o / 12;
    float m = stats[2 * g] * invN;
    float var = stats[2 * g + 1] * invN - m * m;
    float val = (y[((size_t)(b * 96 + o) << 15) + v0 + v] - m) * rsqrtf(var + 1e-5f) * gg[o] + gb[o];
    sT[v][ol] = 0.5f * val * (1.f + erff(val * 0.70710678118654752f));
  }
  __syncthreads();
  for (int id = tid; id < 1024; id += 256) {
    int v = id >> 4, p = id & 15;
    unsigned pk = (unsigned)f2bf(sT[v][2 * p]) | ((unsigned)f2bf(sT[v][2 * p + 1]) << 16);
    ((unsigned*)xt)[((size_t)(b * 3 + c) * 32768 + v0 + v) * 16 + p] = pk;
  }
}

// ---------------- reconstruct + baseline z-interp (reads bf16 transposed f5) ----------------
__global__ __launch_bounds__(256) void k_final(const short* __restrict__ f5b, const float* __restrict__ sp,
    const float* __restrict__ rw, const float* __restrict__ rb, const int* __restrict__ T,
    float* __restrict__ out) {
  int x = blockIdx.x;
  int b = x >> 10, chunk = x & 1023;
  int z = chunk >> 5, h = chunk & 31;
  int v0 = chunk * 32;
  __shared__ float sF[96][32];
  int tid = threadIdx.x;
  for (int id = tid; id < 1536; id += 256) {
    int c = id / 512, r2 = id % 512;
    int wv = r2 >> 4, p = r2 & 15;
    unsigned u = ((const unsigned*)f5b)[((size_t)(b * 3 + c) * 32768 + v0 + wv) * 16 + p];
    sF[c * 32 + 2 * p][wv] = bfl(u);
    sF[c * 32 + 2 * p + 1][wv] = bfh(u);
  }
  __syncthreads();
  const float* w64 = (const float*)(T + 128);
  for (int it = 0; it < 16; it++) {
    int id = tid + 256 * it;
    int wv = id >> 7, j = id & 127;
    int o = j >> 5, dd = (j >> 4) & 1, e = (j >> 2) & 3, ff = j & 3;
    float acc = 0.f;
    for (int i = 0; i < 96; i++) acc += sF[i][wv] * rw[i * 128 + j];
    int Z = 2 * z + dd, H = 4 * h + e, W = 4 * wv + ff;
    int zl = T[Z], zr = T[64 + Z];
    float bw = w64[Z];
    const float* spb = sp + (size_t)(b * 4 + o) * 12 * 16384;
    float bval = (1.f - bw) * spb[(size_t)zl * 16384 + H * 128 + W]
               + bw * spb[(size_t)zr * 16384 + H * 128 + W];
    out[((size_t)(b * 4 + o) * 64 + Z) * 16384 + H * 128 + W] = bval + acc + rb[o];
  }
}

extern "C" void kernel_launch(void* const* d_in, const int* in_sizes, int n_in,
                              void* d_out, int out_size, void* d_ws, size_t ws_size,
                              hipStream_t stream) {
  const float* sp    = (const float*)d_in[0];
  const float* ef    = (const float*)d_in[1];
  const float* pe_w  = (const float*)d_in[2];
  const float* pe_b  = (const float*)d_in[3];
  const float* pe_g  = (const float*)d_in[4];
  const float* pe_be = (const float*)d_in[5];
  const float* enc_w = (const float*)d_in[6];
  const float* enc_b = (const float*)d_in[7];
  const float* ln_g  = (const float*)d_in[8];
  const float* ln_b  = (const float*)d_in[9];
  const float* qkv_w = (const float*)d_in[10];
  const float* qkv_b = (const float*)d_in[11];
  const float* at_w  = (const float*)d_in[12];
  const float* at_b  = (const float*)d_in[13];
  const float* rpb   = (const float*)d_in[14];
  const float* w1    = (const float*)d_in[15];
  const float* b1    = (const float*)d_in[16];
  const float* g1g   = (const float*)d_in[17];
  const float* g1b   = (const float*)d_in[18];
  const float* w2    = (const float*)d_in[19];
  const float* b2    = (const float*)d_in[20];
  const float* g2g   = (const float*)d_in[21];
  const float* g2b   = (const float*)d_in[22];
  const float* recw  = (const float*)d_in[23];
  const float* recb  = (const float*)d_in[24];
  const int*   sidx  = (const int*)d_in[25];
  float* out = (float*)d_out;

  char* ws = (char*)d_ws;
  const size_t BIG = 50331648; // 4*96*32768*4 bytes
  float* A  = (float*)ws;                 // f2 -> y1 -> y2
  float* Bf = (float*)(ws + BIG);         // f1 -> Xt1(bf16) -> Xt2(bf16) -> f5b(bf16)
  int*   T  = (int*)(ws + 2 * BIG);
  float* stats = (float*)(ws + 2 * BIG + 4096);
  // bf16 weights live in d_out tail (overwritten by k_final at the end)
  short* Wt1 = (short*)((char*)d_out + 66060288);
  short* Wt2 = Wt1 + 248832;

  k_tables<<<1, 96, 0, stream>>>(sidx, T);
  k_wcv<<<972, 256, 0, stream>>>(w1, Wt1);
  k_wcv<<<972, 256, 0, stream>>>(w2, Wt2);

  k_pe<<<1536, 256, 0, stream>>>(sp, pe_w, pe_b, pe_g, pe_be, Bf);
  k_ie<<<2048, 256, 0, stream>>>(Bf, ef, enc_w, enc_b, T, A);
  k_attn<<<2048, 256, 0, stream>>>(A, ln_g, ln_b, qkv_w, qkv_b, at_w, at_b, rpb, (short*)Bf);

  k_convM<<<512, 512, 0, stream>>>((const short*)Bf, Wt1, b1, A);
  hipMemsetAsync(stats, 0, 64 * sizeof(float), stream);
  k_stats<<<6144, 256, 0, stream>>>(A, stats);
  k_gn<<<6144, 256, 0, stream>>>(A, stats, g1g, g1b, (short*)Bf);

  k_convM<<<512, 512, 0, stream>>>((const short*)Bf, Wt2, b2, A);
  hipMemsetAsync(stats, 0, 64 * sizeof(float), stream);
  k_stats<<<6144, 256, 0, stream>>>(A, stats);
  k_gn<<<6144, 256, 0, stream>>>(A, stats, g2g, g2b, (short*)Bf);

  k_final<<<4096, 256, 0, stream>>>((const short*)Bf, sp, recw, recb, T, out);
}

// Round 3
// 1090.618 us; speedup vs baseline: 13.4813x; 3.1022x over previous
//
#include <hip/hip_runtime.h>
#include <math.h>

typedef __attribute__((ext_vector_type(8))) short short8v;
typedef __attribute__((ext_vector_type(4))) float float4v;

__device__ inline unsigned short f2bf(float f) {
  unsigned u = __float_as_uint(f);
  return (unsigned short)((u + 0x7fff + ((u >> 16) & 1)) >> 16);
}
__device__ inline unsigned pk2(float a, float b) {
  return (unsigned)f2bf(a) | ((unsigned)f2bf(b) << 16);
}
__device__ inline float bfl(unsigned u) { return __uint_as_float(u << 16); }
__device__ inline float bfh(unsigned u) { return __uint_as_float(u & 0xffff0000u); }
__device__ inline float bfs(short s) { return __uint_as_float(((unsigned)(unsigned short)s) << 16); }

// ---------------- tables ----------------
__global__ __launch_bounds__(96) void k_tables(const int* __restrict__ sidx, int* __restrict__ T) {
  __shared__ float pos[12];
  int t = threadIdx.x;
  if (t < 12) pos[t] = (float)sidx[t];
  __syncthreads();
  if (t < 64) {
    float zq = (float)t;
    int r = 0;
    while (r < 12 && pos[r] < zq) r++;
    int l = r - 1; if (l < 0) l = 0; if (l > 11) l = 11;
    int rc = r; if (rc > 11) rc = 11;
    float lp = pos[l], rp = pos[rc], d = rp - lp;
    float w = d > 0.f ? (zq - lp) / d : 0.5f;
    T[t] = l; T[64 + t] = rc; ((float*)T)[128 + t] = w;
  } else {
    int zq = t - 64;
    float zqf = (float)zq;
    int r = 0;
    while (r < 12 && pos[r] * 0.5f < zqf) r++;
    int l = r - 1; if (l < 0) l = 0; if (l > 11) l = 11;
    int rc = r; if (rc > 11) rc = 11;
    float lp = pos[l] * 0.5f, rp = pos[rc] * 0.5f, d = rp - lp;
    float w = d > 0.f ? (zqf - lp) / d : 0.5f;
    T[192 + zq] = l; T[224 + zq] = rc; ((float*)T)[256 + zq] = w;
  }
}

// ---------------- conv weight convert: [o][i][27] f32 -> [tap][o][i] bf16 ----------------
__global__ __launch_bounds__(256) void k_wcv(const float* __restrict__ w, short* __restrict__ Wt) {
  int id = blockIdx.x * 256 + threadIdx.x;
  if (id >= 248832) return;
  float v = w[id];
  int o = id / 2592; int rem = id % 2592; int i = rem / 27; int tap = rem % 27;
  Wt[(tap * 96 + o) * 96 + i] = (short)f2bf(v);
}

// ---------------- generic f32 -> bf16 ----------------
__global__ __launch_bounds__(256) void k_cvt(const float* __restrict__ src, short* __restrict__ dst, int n) {
  int id = blockIdx.x * 256 + threadIdx.x;
  if (id < n) dst[id] = (short)f2bf(src[id]);
}

// ---------------- expand rel-pos bias: Bt[head][n][m] ----------------
__global__ __launch_bounds__(256) void k_bias(const float* __restrict__ rpb, float* __restrict__ Bt) {
  int id = blockIdx.x * 256 + threadIdx.x;
  if (id >= 12288) return;
  int head = id >> 12, rem = id & 4095, n = rem >> 6, m = rem & 63;
  int dz = (n >> 4) - (m >> 4), dh = ((n >> 2) & 3) - ((m >> 2) & 3), dw = (n & 3) - (m & 3);
  Bt[id] = rpb[((dz + 3) * 49 + (dh + 3) * 7 + (dw + 3)) * 3 + head];
}

// ---------------- patch embed + LayerNorm ----------------
__global__ __launch_bounds__(256) void k_pe(const float* __restrict__ sp, const float* __restrict__ pw,
    const float* __restrict__ pb, const float* __restrict__ pg, const float* __restrict__ pbeta,
    float* __restrict__ f1) {
  int x = blockIdx.x;
  int b = x / 384, z = (x / 32) % 12, h = x % 32;
  __shared__ float sIn[4][4][128];
  __shared__ float sF[32][97];
  __shared__ float sM[32], sR[32];
  int tid = threadIdx.x;
  for (int id = tid; id < 2048; id += 256) {
    int c = id >> 9, p = (id >> 7) & 3, col = id & 127;
    sIn[c][p][col] = sp[(((b * 4 + c) * 12 + z) * 128 + h * 4 + p) * 128 + col];
  }
  __syncthreads();
  for (int id = tid; id < 3072; id += 256) {
    int w = id / 96, d = id % 96;
    float acc = pb[d];
    #pragma unroll
    for (int c = 0; c < 4; c++)
      #pragma unroll
      for (int p = 0; p < 4; p++)
        #pragma unroll
        for (int q = 0; q < 4; q++)
          acc += sIn[c][p][w * 4 + q] * pw[((d * 4 + c) * 4 + p) * 4 + q];
    sF[w][d] = acc;
  }
  __syncthreads();
  if (tid < 32) {
    int w = tid;
    float s = 0.f, ss = 0.f;
    for (int d = 0; d < 96; d++) { float v = sF[w][d]; s += v; ss += v * v; }
    float m = s * (1.f / 96.f);
    float var = ss * (1.f / 96.f) - m * m;
    sM[w] = m; sR[w] = rsqrtf(var + 1e-5f);
  }
  __syncthreads();
  for (int id = tid; id < 3072; id += 256) {
    int d = id >> 5, w = id & 31;
    float v = (sF[w][d] - sM[w]) * sR[w] * pg[d] + pbeta[d];
    f1[(((b * 96 + d) * 12 + z) * 32 + h) * 32 + w] = v;
  }
}

// ---------------- z-interp 12->32 + encoder proj -> X token-major bf16 [win*64+t][96] ----------------
__global__ __launch_bounds__(256) void k_ie(const float* __restrict__ f1, const float* __restrict__ ef,
    const float* __restrict__ ew, const float* __restrict__ eb, const int* __restrict__ T,
    unsigned* __restrict__ Xg) {
  int x = blockIdx.x;
  int b = x >> 9, chunk = x & 511;
  int v0 = chunk * 64;
  int z = v0 >> 10, rp = v0 & 1023;
  int zl = T[192 + z], zr = T[224 + z];
  float wt = ((const float*)T)[256 + z];
  __shared__ float sE[96][64];
  __shared__ float sR[96][67];
  int tid = threadIdx.x;
  for (int id = tid; id < 6144; id += 256) {
    int c = id >> 6, vs = id & 63;
    sE[c][vs] = ef[(b * 96 + c) * 32768 + v0 + vs];
  }
  __syncthreads();
  for (int id = tid; id < 6144; id += 256) {
    int d = id >> 6, vs = id & 63;
    float acc = eb[d];
    for (int c = 0; c < 96; c++) acc += sE[c][vs] * ew[d * 96 + c];
    const float* p1 = f1 + ((size_t)(b * 96 + d) * 12 + zl) * 1024 + rp + vs;
    const float* p2 = f1 + ((size_t)(b * 96 + d) * 12 + zr) * 1024 + rp + vs;
    sR[d][vs] = (1.f - wt) * p1[0] + wt * p2[0] + acc;
  }
  __syncthreads();
  int h0 = (chunk & 15) * 2;
  int zb = z >> 2, tz = z & 3;
  for (int id = tid; id < 3072; id += 256) {
    int vs = id / 48, c2 = id % 48;
    int h = h0 + (vs >> 5), w = vs & 31;
    int win = ((b * 8 + zb) * 8 + (h >> 2)) * 8 + (w >> 2);
    int t = tz * 16 + (h & 3) * 4 + (w & 3);
    Xg[(size_t)(win * 64 + t) * 48 + c2] = pk2(sR[2 * c2][vs], sR[2 * c2 + 1][vs]);
  }
}

// ---------------- LN + QKV projection (MFMA), Q/K [wh][tok][32], V^T [wh][c][tok] ----------------
__global__ __launch_bounds__(512) void k_qkv(const unsigned* __restrict__ Xg, const short* __restrict__ Wq,
    const float* __restrict__ qb, const float* __restrict__ lg, const float* __restrict__ lb,
    short* __restrict__ Qg, short* __restrict__ Kg, short* __restrict__ Vg) {
  int win = blockIdx.x;
  __shared__ short sX[64][104];
  __shared__ short sVt[96][72];
  __shared__ float sM[64], sRr[64];
  int tid = threadIdx.x;
  for (int id = tid; id < 3072; id += 512) {
    int row = id / 48, c2 = id % 48;
    *(unsigned*)&sX[row][c2 * 2] = Xg[(size_t)(win * 64 + row) * 48 + c2];
  }
  __syncthreads();
  {
    int token = tid >> 3, j = tid & 7;
    float s = 0.f, ss = 0.f;
    #pragma unroll
    for (int i = 0; i < 12; i++) {
      float v = bfs(sX[token][j * 12 + i]);
      s += v; ss += v * v;
    }
    s += __shfl_xor(s, 1); ss += __shfl_xor(ss, 1);
    s += __shfl_xor(s, 2); ss += __shfl_xor(ss, 2);
    s += __shfl_xor(s, 4); ss += __shfl_xor(ss, 4);
    if (j == 0) {
      float m = s * (1.f / 96.f);
      sM[token] = m;
      sRr[token] = rsqrtf(ss * (1.f / 96.f) - m * m + 1e-5f);
    }
  }
  __syncthreads();
  for (int id = tid; id < 3072; id += 512) {
    int row = id / 48, c2 = id % 48;
    unsigned u = *(unsigned*)&sX[row][c2 * 2];
    float m = sM[row], r = sRr[row];
    float v0 = (bfl(u) - m) * r * lg[2 * c2] + lb[2 * c2];
    float v1 = (bfh(u) - m) * r * lg[2 * c2 + 1] + lb[2 * c2 + 1];
    *(unsigned*)&sX[row][c2 * 2] = pk2(v0, v1);
  }
  __syncthreads();
  int w = tid >> 6, l = tid & 63, lo = l & 15, ig = l >> 4;
  int mt2 = w >> 1, nh = w & 1;
  short8v a[3];
  #pragma unroll
  for (int kc = 0; kc < 3; kc++)
    a[kc] = *(const short8v*)&sX[mt2 * 16 + lo][kc * 32 + ig * 8];
  for (int nt = nh * 9; nt < nh * 9 + 9; nt++) {
    float4v acc = (float4v){0.f, 0.f, 0.f, 0.f};
    #pragma unroll
    for (int kc = 0; kc < 3; kc++) {
      short8v bfr = *(const short8v*)(Wq + (size_t)(nt * 16 + lo) * 96 + kc * 32 + ig * 8);
      acc = __builtin_amdgcn_mfma_f32_16x16x32_bf16(a[kc], bfr, acc, 0, 0, 0);
    }
    int out = nt * 16 + lo;
    float bias = qb[out];
    if (nt < 6) {
      int head = out >> 5, c = out & 31;
      #pragma unroll
      for (int r = 0; r < 4; r++)
        Qg[((size_t)(win * 3 + head) * 64 + mt2 * 16 + ig * 4 + r) * 32 + c] =
            (short)f2bf((acc[r] + bias) * 0.17677669529663687f);
    } else if (nt < 12) {
      int o2 = out - 96, head = o2 >> 5, c = o2 & 31;
      #pragma unroll
      for (int r = 0; r < 4; r++)
        Kg[((size_t)(win * 3 + head) * 64 + mt2 * 16 + ig * 4 + r) * 32 + c] = (short)f2bf(acc[r] + bias);
    } else {
      int o2 = out - 192;
      #pragma unroll
      for (int r = 0; r < 4; r++)
        sVt[o2][mt2 * 16 + ig * 4 + r] = (short)f2bf(acc[r] + bias);
    }
  }
  __syncthreads();
  for (int id = tid; id < 768; id += 512) {
    int row = id >> 3, ch = id & 7;
    short8v v = *(short8v*)&sVt[row][ch * 8];
    *(short8v*)(Vg + ((size_t)(win * 3 + (row >> 5)) * 32 + (row & 31)) * 64 + ch * 8) = v;
  }
}

// ---------------- attention core: 1 wave = 1 window-head ----------------
__global__ __launch_bounds__(256) void k_att2(const short* __restrict__ Qg, const short* __restrict__ Kg,
    const short* __restrict__ Vg, const float* __restrict__ Bt, short* __restrict__ Og) {
  __shared__ short Pl[4][64][72];
  int tid = threadIdx.x;
  int w = tid >> 6, l = tid & 63, lo = l & 15, ig = l >> 4;
  int gwh = blockIdx.x * 4 + w;
  int head = gwh % 3, win = gwh / 3;
  short8v q[4], k[4];
  #pragma unroll
  for (int mt = 0; mt < 4; mt++)
    q[mt] = *(const short8v*)(Qg + ((size_t)gwh * 64 + mt * 16 + lo) * 32 + ig * 8);
  #pragma unroll
  for (int nt = 0; nt < 4; nt++)
    k[nt] = *(const short8v*)(Kg + ((size_t)gwh * 64 + nt * 16 + lo) * 32 + ig * 8);
  float4v s[4][4];
  #pragma unroll
  for (int mt = 0; mt < 4; mt++)
    #pragma unroll
    for (int nt = 0; nt < 4; nt++)
      s[mt][nt] = __builtin_amdgcn_mfma_f32_16x16x32_bf16(q[mt], k[nt], (float4v){0.f, 0.f, 0.f, 0.f}, 0, 0, 0);
  const float* bt = Bt + head * 4096;
  #pragma unroll
  for (int mt = 0; mt < 4; mt++) {
    #pragma unroll
    for (int r = 0; r < 4; r++) {
      int tok = mt * 16 + ig * 4 + r;
      float v[4];
      float mx = -1e30f;
      #pragma unroll
      for (int nt = 0; nt < 4; nt++) {
        v[nt] = s[mt][nt][r] + bt[tok * 64 + nt * 16 + lo];
        mx = fmaxf(mx, v[nt]);
      }
      mx = fmaxf(mx, __shfl_xor(mx, 1));
      mx = fmaxf(mx, __shfl_xor(mx, 2));
      mx = fmaxf(mx, __shfl_xor(mx, 4));
      mx = fmaxf(mx, __shfl_xor(mx, 8));
      float sm = 0.f;
      #pragma unroll
      for (int nt = 0; nt < 4; nt++) { v[nt] = __expf(v[nt] - mx); sm += v[nt]; }
      sm += __shfl_xor(sm, 1);
      sm += __shfl_xor(sm, 2);
      sm += __shfl_xor(sm, 4);
      sm += __shfl_xor(sm, 8);
      float inv = 1.f / sm;
      #pragma unroll
      for (int nt = 0; nt < 4; nt++)
        Pl[w][tok][nt * 16 + lo] = (short)f2bf(v[nt] * inv);
    }
  }
  short8v pa[4][2], vb[2][2];
  #pragma unroll
  for (int mt = 0; mt < 4; mt++)
    #pragma unroll
    for (int kc = 0; kc < 2; kc++)
      pa[mt][kc] = *(const short8v*)&Pl[w][mt * 16 + lo][kc * 32 + ig * 8];
  #pragma unroll
  for (int ct = 0; ct < 2; ct++)
    #pragma unroll
    for (int kc = 0; kc < 2; kc++)
      vb[ct][kc] = *(const short8v*)(Vg + ((size_t)gwh * 32 + ct * 16 + lo) * 64 + kc * 32 + ig * 8);
  #pragma unroll
  for (int mt = 0; mt < 4; mt++)
    #pragma unroll
    for (int ct = 0; ct < 2; ct++) {
      float4v o = __builtin_amdgcn_mfma_f32_16x16x32_bf16(pa[mt][0], vb[ct][0], (float4v){0.f, 0.f, 0.f, 0.f}, 0, 0, 0);
      o = __builtin_amdgcn_mfma_f32_16x16x32_bf16(pa[mt][1], vb[ct][1], o, 0, 0, 0);
      #pragma unroll
      for (int r = 0; r < 4; r++)
        Og[((size_t)(win * 64 + mt * 16 + ig * 4 + r)) * 96 + head * 32 + ct * 16 + lo] = (short)f2bf(o[r]);
    }
}

// ---------------- proj + residual -> conv-layout bf16 ----------------
__global__ __launch_bounds__(256) void k_proj(const short* __restrict__ Og, const unsigned* __restrict__ Xg,
    const short* __restrict__ Wa, const float* __restrict__ ab, short* __restrict__ Xt) {
  int win = blockIdx.x;
  __shared__ float sOut[64][100];
  int tid = threadIdx.x;
  int w = tid >> 6, l = tid & 63, lo = l & 15, ig = l >> 4;
  int mt = w;
  short8v a[3];
  #pragma unroll
  for (int kc = 0; kc < 3; kc++)
    a[kc] = *(const short8v*)(Og + ((size_t)(win * 64 + mt * 16 + lo)) * 96 + kc * 32 + ig * 8);
  #pragma unroll
  for (int nt = 0; nt < 6; nt++) {
    float4v acc = (float4v){0.f, 0.f, 0.f, 0.f};
    #pragma unroll
    for (int kc = 0; kc < 3; kc++) {
      short8v bfr = *(const short8v*)(Wa + (size_t)(nt * 16 + lo) * 96 + kc * 32 + ig * 8);
      acc = __builtin_amdgcn_mfma_f32_16x16x32_bf16(a[kc], bfr, acc, 0, 0, 0);
    }
    int out = nt * 16 + lo;
    float bias = ab[out];
    #pragma unroll
    for (int r = 0; r < 4; r++) {
      int tok = mt * 16 + ig * 4 + r;
      unsigned u = Xg[(size_t)(win * 64 + tok) * 48 + (out >> 1)];
      sOut[tok][out] = acc[r] + bias + ((out & 1) ? bfh(u) : bfl(u));
    }
  }
  __syncthreads();
  int b = win >> 9, zb = (win >> 6) & 7, hb = (win >> 3) & 7, wb = win & 7;
  for (int id = tid; id < 3072; id += 256) {
    int cc = id >> 10, rem = id & 1023, t = rem >> 4, ilp = rem & 15;
    int d0 = cc * 32 + ilp * 2;
    unsigned pk = pk2(sOut[t][d0], sOut[t][d0 + 1]);
    int tz = t >> 4, th = (t >> 2) & 3, tw = t & 3;
    size_t vox = (size_t)(zb * 4 + tz) * 1024 + (hb * 4 + th) * 32 + wb * 4 + tw;
    ((unsigned*)Xt)[((size_t)(b * 3 + cc) * 32768 + vox) * 16 + ilp] = pk;
  }
}

// ---------------- MFMA conv 3x3x3 ----------------
__global__ __launch_bounds__(512) void k_convM(const short* __restrict__ Xt,
    const short* __restrict__ Wt, const float* __restrict__ cb, float* __restrict__ y) {
  int x = blockIdx.x;
  int b = x >> 7, z = (x >> 2) & 31, hq = x & 3;
  int tid = threadIdx.x;
  int wv = tid >> 6, l = tid & 63;
  int lo = l & 15, ig = l >> 4;
  __shared__ short Xl[32640];   // [3z][10h][34w][32i]
  float4v acc[6][2];
  #pragma unroll
  for (int m = 0; m < 6; m++)
    #pragma unroll
    for (int n = 0; n < 2; n++) acc[m][n] = (float4v){0.f, 0.f, 0.f, 0.f};

  for (int c = 0; c < 3; c++) {
    __syncthreads();
    for (int r = 0; r < 8; r++) {
      int id = tid + 512 * r;
      if (id < 4080) {
        int seg = id & 3, q = id >> 2;
        int zz = q / 340, rem = q - zz * 340;
        int hh = rem / 34, ww = rem - hh * 34;
        int gz = z + zz - 1, gh = hq * 8 + hh - 1, gw = ww - 1;
        int4 val = {0, 0, 0, 0};
        if (gz >= 0 && gz < 32 && gh >= 0 && gh < 32 && gw >= 0 && gw < 32)
          val = *(const int4*)(Xt + ((size_t)((b * 3 + c) * 32768 + (gz << 10) + (gh << 5) + gw) * 32 + seg * 8));
        *(int4*)(&Xl[q * 32 + seg * 8]) = val;
      }
    }
    __syncthreads();
    for (int tap = 0; tap < 27; tap++) {
      int dz = tap / 9, dh = (tap % 9) / 3, dwv = tap % 3;
      short8v a[6];
      #pragma unroll
      for (int m = 0; m < 6; m++)
        a[m] = *reinterpret_cast<const short8v*>(Wt + ((size_t)(tap * 96 + m * 16 + lo)) * 96 + c * 32 + ig * 8);
      #pragma unroll
      for (int n = 0; n < 2; n++) {
        int baddr = ((dz * 10 + wv + dh) * 34 + n * 16 + lo + dwv) * 32 + ig * 8;
        short8v bf = *reinterpret_cast<const short8v*>(&Xl[baddr]);
        #pragma unroll
        for (int m = 0; m < 6; m++)
          acc[m][n] = __builtin_amdgcn_mfma_f32_16x16x32_bf16(a[m], bf, acc[m][n], 0, 0, 0);
      }
    }
  }
  int h = hq * 8 + wv;
  #pragma unroll
  for (int m = 0; m < 6; m++)
    #pragma unroll
    for (int n = 0; n < 2; n++)
      #pragma unroll
      for (int r = 0; r < 4; r++) {
        int o = m * 16 + ig * 4 + r;
        int vcol = n * 16 + lo;
        y[((size_t)(b * 96 + o) << 15) + (z << 10) + (h << 5) + vcol] = acc[m][n][r] + cb[o];
      }
}

// ---------------- GN stats ----------------
__global__ __launch_bounds__(256) void k_stats(const float* __restrict__ y, float* __restrict__ stats) {
  int x = blockIdx.x;
  int bo = x >> 4, seg = x & 15;
  int b = bo / 96, o = bo % 96;
  const float* p = y + (size_t)bo * 32768 + seg * 2048;
  int tid = threadIdx.x;
  float s = 0.f, ss = 0.f;
  #pragma unroll
  for (int r = 0; r < 2; r++) {
    float4 v = ((const float4*)p)[tid + 256 * r];
    s += v.x + v.y + v.z + v.w;
    ss += v.x * v.x + v.y * v.y + v.z * v.z + v.w * v.w;
  }
  __shared__ float rs[256], rss[256];
  rs[tid] = s; rss[tid] = ss;
  __syncthreads();
  for (int st = 128; st > 0; st >>= 1) {
    if (tid < st) { rs[tid] += rs[tid + st]; rss[tid] += rss[tid + st]; }
    __syncthreads();
  }
  if (tid == 0) {
    int g = b * 8 + o / 12;
    atomicAdd(&stats[2 * g], rs[0]);
    atomicAdd(&stats[2 * g + 1], rss[0]);
  }
}

// ---------------- GN apply + GELU -> bf16 conv layout ----------------
__global__ __launch_bounds__(256) void k_gn(const float* __restrict__ y, const float* __restrict__ stats,
    const float* __restrict__ gg, const float* __restrict__ gb, short* __restrict__ xt) {
  int x = blockIdx.x;
  int b = x / 1536, r = x % 1536, c = r / 512, vt = r % 512;
  int v0 = vt * 64;
  __shared__ float sT[64][33];
  int tid = threadIdx.x;
  const float invN = 1.f / 393216.f;
  for (int id = tid; id < 2048; id += 256) {
    int ol = id >> 6, v = id & 63;
    int o = c * 32 + ol, g = b * 8 + o / 12;
    float m = stats[2 * g] * invN;
    float var = stats[2 * g + 1] * invN - m * m;
    float val = (y[((size_t)(b * 96 + o) << 15) + v0 + v] - m) * rsqrtf(var + 1e-5f) * gg[o] + gb[o];
    sT[v][ol] = 0.5f * val * (1.f + erff(val * 0.70710678118654752f));
  }
  __syncthreads();
  for (int id = tid; id < 1024; id += 256) {
    int v = id >> 4, p = id & 15;
    ((unsigned*)xt)[((size_t)(b * 3 + c) * 32768 + v0 + v) * 16 + p] = pk2(sT[v][2 * p], sT[v][2 * p + 1]);
  }
}

// ---------------- reconstruct + baseline z-interp ----------------
__global__ __launch_bounds__(256) void k_final(const short* __restrict__ f5b, const float* __restrict__ sp,
    const float* __restrict__ rw, const float* __restrict__ rb, const int* __restrict__ T,
    float* __restrict__ out) {
  int x = blockIdx.x;
  int b = x >> 10, chunk = x & 1023;
  int z = chunk >> 5, h = chunk & 31;
  int v0 = chunk * 32;
  __shared__ float sF[96][32];
  int tid = threadIdx.x;
  for (int id = tid; id < 1536; id += 256) {
    int c = id / 512, r2 = id % 512;
    int wv = r2 >> 4, p = r2 & 15;
    unsigned u = ((const unsigned*)f5b)[((size_t)(b * 3 + c) * 32768 + v0 + wv) * 16 + p];
    sF[c * 32 + 2 * p][wv] = bfl(u);
    sF[c * 32 + 2 * p + 1][wv] = bfh(u);
  }
  __syncthreads();
  const float* w64 = (const float*)(T + 128);
  for (int it = 0; it < 16; it++) {
    int id = tid + 256 * it;
    int wv = id >> 7, j = id & 127;
    int o = j >> 5, dd = (j >> 4) & 1, e = (j >> 2) & 3, ff = j & 3;
    float acc = 0.f;
    for (int i = 0; i < 96; i++) acc += sF[i][wv] * rw[i * 128 + j];
    int Z = 2 * z + dd, H = 4 * h + e, W = 4 * wv + ff;
    int zl = T[Z], zr = T[64 + Z];
    float bw = w64[Z];
    const float* spb = sp + (size_t)(b * 4 + o) * 12 * 16384;
    float bval = (1.f - bw) * spb[(size_t)zl * 16384 + H * 128 + W]
               + bw * spb[(size_t)zr * 16384 + H * 128 + W];
    out[((size_t)(b * 4 + o) * 64 + Z) * 16384 + H * 128 + W] = bval + acc + rb[o];
  }
}

extern "C" void kernel_launch(void* const* d_in, const int* in_sizes, int n_in,
                              void* d_out, int out_size, void* d_ws, size_t ws_size,
                              hipStream_t stream) {
  const float* sp    = (const float*)d_in[0];
  const float* ef    = (const float*)d_in[1];
  const float* pe_w  = (const float*)d_in[2];
  const float* pe_b  = (const float*)d_in[3];
  const float* pe_g  = (const float*)d_in[4];
  const float* pe_be = (const float*)d_in[5];
  const float* enc_w = (const float*)d_in[6];
  const float* enc_b = (const float*)d_in[7];
  const float* ln_g  = (const float*)d_in[8];
  const float* ln_b  = (const float*)d_in[9];
  const float* qkv_w = (const float*)d_in[10];
  const float* qkv_b = (const float*)d_in[11];
  const float* at_w  = (const float*)d_in[12];
  const float* at_b  = (const float*)d_in[13];
  const float* rpb   = (const float*)d_in[14];
  const float* w1    = (const float*)d_in[15];
  const float* b1    = (const float*)d_in[16];
  const float* g1g   = (const float*)d_in[17];
  const float* g1b   = (const float*)d_in[18];
  const float* w2    = (const float*)d_in[19];
  const float* b2    = (const float*)d_in[20];
  const float* g2g   = (const float*)d_in[21];
  const float* g2b   = (const float*)d_in[22];
  const float* recw  = (const float*)d_in[23];
  const float* recb  = (const float*)d_in[24];
  const int*   sidx  = (const int*)d_in[25];
  float* out = (float*)d_out;

  char* ws = (char*)d_ws;
  unsigned* Xg = (unsigned*)ws;                    // X bf16-pairs [131072][48]
  float* f1    = (float*)(ws + 25165824);          // dead before k_qkv
  short* Qg    = (short*)(ws + 25165824);
  short* Kg    = (short*)(ws + 50331648);
  short* Vg    = (short*)(ws + 75497472);
  short* XtA   = (short*)(ws + 25165824);          // conv-layout bf16 (after QKV dead)
  float* Y     = (float*)(ws + 50331648);          // conv out fp32
  int*   T     = (int*)(ws + 100663296);
  float* stats = (float*)(ws + 100665344);

  char* dob = (char*)d_out;
  short* Og   = (short*)d_out;                     // [win][64][96] bf16, dead space until k_final
  short* Wqkv = (short*)(dob + 65937408);
  short* Waw  = (short*)(dob + 65992704);
  float* Bt   = (float*)(dob + 66011136);
  short* Wt1  = (short*)(dob + 66060288);
  short* Wt2  = (short*)(dob + 66557952);

  k_tables<<<1, 96, 0, stream>>>(sidx, T);
  k_wcv<<<972, 256, 0, stream>>>(w1, Wt1);
  k_wcv<<<972, 256, 0, stream>>>(w2, Wt2);
  k_cvt<<<108, 256, 0, stream>>>(qkv_w, Wqkv, 27648);
  k_cvt<<<36, 256, 0, stream>>>(at_w, Waw, 9216);
  k_bias<<<48, 256, 0, stream>>>(rpb, Bt);

  k_pe<<<1536, 256, 0, stream>>>(sp, pe_w, pe_b, pe_g, pe_be, f1);
  k_ie<<<2048, 256, 0, stream>>>(f1, ef, enc_w, enc_b, T, Xg);
  k_qkv<<<2048, 512, 0, stream>>>(Xg, Wqkv, qkv_b, ln_g, ln_b, Qg, Kg, Vg);
  k_att2<<<1536, 256, 0, stream>>>(Qg, Kg, Vg, Bt, Og);
  k_proj<<<2048, 256, 0, stream>>>(Og, Xg, Waw, at_b, XtA);

  k_convM<<<512, 512, 0, stream>>>(XtA, Wt1, b1, Y);
  hipMemsetAsync(stats, 0, 64 * sizeof(float), stream);
  k_stats<<<6144, 256, 0, stream>>>(Y, stats);
  k_gn<<<6144, 256, 0, stream>>>(Y, stats, g1g, g1b, XtA);

  k_convM<<<512, 512, 0, stream>>>(XtA, Wt2, b2, Y);
  hipMemsetAsync(stats, 0, 64 * sizeof(float), stream);
  k_stats<<<6144, 256, 0, stream>>>(Y, stats);
  k_gn<<<6144, 256, 0, stream>>>(Y, stats, g2g, g2b, XtA);

  k_final<<<4096, 256, 0, stream>>>(XtA, sp, recw, recb, T, out);
}

// Round 4
// 686.604 us; speedup vs baseline: 21.4139x; 1.5884x over previous
//
#include <hip/hip_runtime.h>
#include <math.h>

typedef __attribute__((ext_vector_type(8))) short short8v;
typedef __attribute__((ext_vector_type(4))) float float4v;

__device__ inline unsigned short f2bf(float f) {
  unsigned u = __float_as_uint(f);
  return (unsigned short)((u + 0x7fff + ((u >> 16) & 1)) >> 16);
}
__device__ inline unsigned pk2(float a, float b) {
  return (unsigned)f2bf(a) | ((unsigned)f2bf(b) << 16);
}
__device__ inline float bfl(unsigned u) { return __uint_as_float(u << 16); }
__device__ inline float bfh(unsigned u) { return __uint_as_float(u & 0xffff0000u); }
__device__ inline float bfs(short s) { return __uint_as_float(((unsigned)(unsigned short)s) << 16); }

// ---------------- tables ----------------
__global__ __launch_bounds__(96) void k_tables(const int* __restrict__ sidx, int* __restrict__ T) {
  __shared__ float pos[12];
  int t = threadIdx.x;
  if (t < 12) pos[t] = (float)sidx[t];
  __syncthreads();
  if (t < 64) {
    float zq = (float)t;
    int r = 0;
    while (r < 12 && pos[r] < zq) r++;
    int l = r - 1; if (l < 0) l = 0; if (l > 11) l = 11;
    int rc = r; if (rc > 11) rc = 11;
    float lp = pos[l], rp = pos[rc], d = rp - lp;
    float w = d > 0.f ? (zq - lp) / d : 0.5f;
    T[t] = l; T[64 + t] = rc; ((float*)T)[128 + t] = w;
  } else {
    int zq = t - 64;
    float zqf = (float)zq;
    int r = 0;
    while (r < 12 && pos[r] * 0.5f < zqf) r++;
    int l = r - 1; if (l < 0) l = 0; if (l > 11) l = 11;
    int rc = r; if (rc > 11) rc = 11;
    float lp = pos[l] * 0.5f, rp = pos[rc] * 0.5f, d = rp - lp;
    float w = d > 0.f ? (zqf - lp) / d : 0.5f;
    T[192 + zq] = l; T[224 + zq] = rc; ((float*)T)[256 + zq] = w;
  }
}

// ---------------- conv weight convert: [o][i][27] f32 -> [tap][o][i] bf16 ----------------
__global__ __launch_bounds__(256) void k_wcv(const float* __restrict__ w, short* __restrict__ Wt) {
  int id = blockIdx.x * 256 + threadIdx.x;
  if (id >= 248832) return;
  float v = w[id];
  int o = id / 2592; int rem = id % 2592; int i = rem / 27; int tap = rem % 27;
  Wt[(tap * 96 + o) * 96 + i] = (short)f2bf(v);
}

// ---------------- generic f32 -> bf16 ----------------
__global__ __launch_bounds__(256) void k_cvt(const float* __restrict__ src, short* __restrict__ dst, int n) {
  int id = blockIdx.x * 256 + threadIdx.x;
  if (id < n) dst[id] = (short)f2bf(src[id]);
}

// ---------------- rec_w [i=96][j=128] f32 -> [j][i] bf16 ----------------
__global__ __launch_bounds__(256) void k_wrt(const float* __restrict__ src, short* __restrict__ dst) {
  int id = blockIdx.x * 256 + threadIdx.x;
  if (id >= 12288) return;
  int i = id >> 7, j = id & 127;
  dst[j * 96 + i] = (short)f2bf(src[id]);
}

// ---------------- expand rel-pos bias: Bt[head][n][m] ----------------
__global__ __launch_bounds__(256) void k_bias(const float* __restrict__ rpb, float* __restrict__ Bt) {
  int id = blockIdx.x * 256 + threadIdx.x;
  if (id >= 12288) return;
  int head = id >> 12, rem = id & 4095, n = rem >> 6, m = rem & 63;
  int dz = (n >> 4) - (m >> 4), dh = ((n >> 2) & 3) - ((m >> 2) & 3), dw = (n & 3) - (m & 3);
  Bt[id] = rpb[((dz + 3) * 49 + (dh + 3) * 7 + (dw + 3)) * 3 + head];
}

// ---------------- patch embed (MFMA) + LayerNorm ----------------
// grid b*12*32, 256 thr; A = Wpe bf16 [d=96][k=64], B = im2col bf16 [w=32][k=64]
__global__ __launch_bounds__(256) void k_pe(const float* __restrict__ sp, const short* __restrict__ Wpe,
    const float* __restrict__ pb, const float* __restrict__ pg, const float* __restrict__ pbeta,
    float* __restrict__ f1) {
  int x = blockIdx.x;
  int b = x / 384, z = (x / 32) % 12, h = x % 32;
  __shared__ short sB[32][72];    // [w][k] pad 72 (144B rows, 16B aligned)
  __shared__ float sF[32][97];
  __shared__ float sM[32], sR[32];
  int tid = threadIdx.x;
  for (int id = tid; id < 2048; id += 256) {
    int c = id >> 9, p = (id >> 7) & 3, col = id & 127;
    float v = sp[(((b * 4 + c) * 12 + z) * 128 + h * 4 + p) * 128 + col];
    sB[col >> 2][c * 16 + p * 4 + (col & 3)] = (short)f2bf(v);
  }
  __syncthreads();
  int w = tid >> 6, l = tid & 63, lo = l & 15, ig = l >> 4;
  int nt = w & 1, mbase = (w >> 1) * 3;
  short8v bfrag[2];
  #pragma unroll
  for (int kc = 0; kc < 2; kc++)
    bfrag[kc] = *(const short8v*)&sB[nt * 16 + lo][kc * 32 + ig * 8];
  #pragma unroll
  for (int mi = 0; mi < 3; mi++) {
    int m = mbase + mi;
    float4v acc = (float4v){0.f, 0.f, 0.f, 0.f};
    #pragma unroll
    for (int kc = 0; kc < 2; kc++) {
      short8v a = *(const short8v*)(Wpe + (size_t)(m * 16 + lo) * 64 + kc * 32 + ig * 8);
      acc = __builtin_amdgcn_mfma_f32_16x16x32_bf16(a, bfrag[kc], acc, 0, 0, 0);
    }
    int wcoord = nt * 16 + lo;
    #pragma unroll
    for (int r = 0; r < 4; r++) {
      int d = m * 16 + ig * 4 + r;
      sF[wcoord][d] = acc[r] + pb[d];
    }
  }
  __syncthreads();
  if (tid < 32) {
    int wv = tid;
    float s = 0.f, ss = 0.f;
    for (int d = 0; d < 96; d++) { float v = sF[wv][d]; s += v; ss += v * v; }
    float m = s * (1.f / 96.f);
    float var = ss * (1.f / 96.f) - m * m;
    sM[wv] = m; sR[wv] = rsqrtf(var + 1e-5f);
  }
  __syncthreads();
  for (int id = tid; id < 3072; id += 256) {
    int d = id >> 5, wv = id & 31;
    float v = (sF[wv][d] - sM[wv]) * sR[wv] * pg[d] + pbeta[d];
    f1[(((b * 96 + d) * 12 + z) * 32 + h) * 32 + wv] = v;
  }
}

// ---------------- z-interp + encoder proj (MFMA) -> X token-major bf16 ----------------
// A = Wenc bf16 [d=96][c=96], B = ef staged bf16 [vox=64][c=96]
__global__ __launch_bounds__(256) void k_ie(const float* __restrict__ f1, const float* __restrict__ ef,
    const short* __restrict__ Wenc, const float* __restrict__ eb, const int* __restrict__ T,
    unsigned* __restrict__ Xg) {
  int x = blockIdx.x;
  int b = x >> 9, chunk = x & 511;
  int v0 = chunk * 64;
  int z = v0 >> 10, rp = v0 & 1023;
  int zl = T[192 + z], zr = T[224 + z];
  float wt = ((const float*)T)[256 + z];
  __shared__ short sEb[64][104];   // [vox][c], 208B rows (16B aligned)
  int tid = threadIdx.x;
  for (int id = tid; id < 6144; id += 256) {
    int c = id >> 6, vs = id & 63;
    sEb[vs][c] = (short)f2bf(ef[(size_t)(b * 96 + c) * 32768 + v0 + vs]);
  }
  __syncthreads();
  int w = tid >> 6, l = tid & 63, lo = l & 15, ig = l >> 4;
  int vcol = w * 16 + lo;
  short8v bfrag[3];
  #pragma unroll
  for (int kc = 0; kc < 3; kc++)
    bfrag[kc] = *(const short8v*)&sEb[vcol][kc * 32 + ig * 8];
  float4v acc[6];
  #pragma unroll
  for (int m = 0; m < 6; m++) {
    acc[m] = (float4v){0.f, 0.f, 0.f, 0.f};
    #pragma unroll
    for (int kc = 0; kc < 3; kc++) {
      short8v a = *(const short8v*)(Wenc + (size_t)(m * 16 + lo) * 96 + kc * 32 + ig * 8);
      acc[m] = __builtin_amdgcn_mfma_f32_16x16x32_bf16(a, bfrag[kc], acc[m], 0, 0, 0);
    }
  }
  int zb = z >> 2, tz = z & 3;
  int h0 = (chunk & 15) * 2;
  int h = h0 + (vcol >> 5), wc = vcol & 31;
  int win = ((b * 8 + zb) * 8 + (h >> 2)) * 8 + (wc >> 2);
  int t = tz * 16 + (h & 3) * 4 + (wc & 3);
  size_t xbase = (size_t)(win * 64 + t) * 48;
  float wl = 1.f - wt;
  #pragma unroll
  for (int m = 0; m < 6; m++) {
    #pragma unroll
    for (int rr = 0; rr < 2; rr++) {
      int d0 = m * 16 + ig * 4 + rr * 2;
      const float* p1a = f1 + ((size_t)(b * 96 + d0) * 12 + zl) * 1024 + rp + vcol;
      const float* p2a = f1 + ((size_t)(b * 96 + d0) * 12 + zr) * 1024 + rp + vcol;
      const float* p1b = f1 + ((size_t)(b * 96 + d0 + 1) * 12 + zl) * 1024 + rp + vcol;
      const float* p2b = f1 + ((size_t)(b * 96 + d0 + 1) * 12 + zr) * 1024 + rp + vcol;
      float va = acc[m][rr * 2] + eb[d0] + wl * p1a[0] + wt * p2a[0];
      float vb = acc[m][rr * 2 + 1] + eb[d0 + 1] + wl * p1b[0] + wt * p2b[0];
      Xg[xbase + m * 8 + ig * 2 + rr] = pk2(va, vb);
    }
  }
}

// ---------------- LN + QKV projection (MFMA) ----------------
__global__ __launch_bounds__(512) void k_qkv(const unsigned* __restrict__ Xg, const short* __restrict__ Wq,
    const float* __restrict__ qb, const float* __restrict__ lg, const float* __restrict__ lb,
    short* __restrict__ Qg, short* __restrict__ Kg, short* __restrict__ Vg) {
  int win = blockIdx.x;
  __shared__ short sX[64][104];
  __shared__ short sVt[96][72];
  __shared__ float sM[64], sRr[64];
  int tid = threadIdx.x;
  for (int id = tid; id < 3072; id += 512) {
    int row = id / 48, c2 = id % 48;
    *(unsigned*)&sX[row][c2 * 2] = Xg[(size_t)(win * 64 + row) * 48 + c2];
  }
  __syncthreads();
  {
    int token = tid >> 3, j = tid & 7;
    float s = 0.f, ss = 0.f;
    #pragma unroll
    for (int i = 0; i < 12; i++) {
      float v = bfs(sX[token][j * 12 + i]);
      s += v; ss += v * v;
    }
    s += __shfl_xor(s, 1); ss += __shfl_xor(ss, 1);
    s += __shfl_xor(s, 2); ss += __shfl_xor(ss, 2);
    s += __shfl_xor(s, 4); ss += __shfl_xor(ss, 4);
    if (j == 0) {
      float m = s * (1.f / 96.f);
      sM[token] = m;
      sRr[token] = rsqrtf(ss * (1.f / 96.f) - m * m + 1e-5f);
    }
  }
  __syncthreads();
  for (int id = tid; id < 3072; id += 512) {
    int row = id / 48, c2 = id % 48;
    unsigned u = *(unsigned*)&sX[row][c2 * 2];
    float m = sM[row], r = sRr[row];
    float v0 = (bfl(u) - m) * r * lg[2 * c2] + lb[2 * c2];
    float v1 = (bfh(u) - m) * r * lg[2 * c2 + 1] + lb[2 * c2 + 1];
    *(unsigned*)&sX[row][c2 * 2] = pk2(v0, v1);
  }
  __syncthreads();
  int w = tid >> 6, l = tid & 63, lo = l & 15, ig = l >> 4;
  int mt2 = w >> 1, nh = w & 1;
  short8v a[3];
  #pragma unroll
  for (int kc = 0; kc < 3; kc++)
    a[kc] = *(const short8v*)&sX[mt2 * 16 + lo][kc * 32 + ig * 8];
  for (int nt = nh * 9; nt < nh * 9 + 9; nt++) {
    float4v acc = (float4v){0.f, 0.f, 0.f, 0.f};
    #pragma unroll
    for (int kc = 0; kc < 3; kc++) {
      short8v bfr = *(const short8v*)(Wq + (size_t)(nt * 16 + lo) * 96 + kc * 32 + ig * 8);
      acc = __builtin_amdgcn_mfma_f32_16x16x32_bf16(a[kc], bfr, acc, 0, 0, 0);
    }
    int out = nt * 16 + lo;
    float bias = qb[out];
    if (nt < 6) {
      int head = out >> 5, c = out & 31;
      #pragma unroll
      for (int r = 0; r < 4; r++)
        Qg[((size_t)(win * 3 + head) * 64 + mt2 * 16 + ig * 4 + r) * 32 + c] =
            (short)f2bf((acc[r] + bias) * 0.17677669529663687f);
    } else if (nt < 12) {
      int o2 = out - 96, head = o2 >> 5, c = o2 & 31;
      #pragma unroll
      for (int r = 0; r < 4; r++)
        Kg[((size_t)(win * 3 + head) * 64 + mt2 * 16 + ig * 4 + r) * 32 + c] = (short)f2bf(acc[r] + bias);
    } else {
      int o2 = out - 192;
      #pragma unroll
      for (int r = 0; r < 4; r++)
        sVt[o2][mt2 * 16 + ig * 4 + r] = (short)f2bf(acc[r] + bias);
    }
  }
  __syncthreads();
  for (int id = tid; id < 768; id += 512) {
    int row = id >> 3, ch = id & 7;
    short8v v = *(short8v*)&sVt[row][ch * 8];
    *(short8v*)(Vg + ((size_t)(win * 3 + (row >> 5)) * 32 + (row & 31)) * 64 + ch * 8) = v;
  }
}

// ---------------- attention core: 1 wave = 1 window-head ----------------
__global__ __launch_bounds__(256) void k_att2(const short* __restrict__ Qg, const short* __restrict__ Kg,
    const short* __restrict__ Vg, const float* __restrict__ Bt, short* __restrict__ Og) {
  __shared__ short Pl[4][64][72];
  int tid = threadIdx.x;
  int w = tid >> 6, l = tid & 63, lo = l & 15, ig = l >> 4;
  int gwh = blockIdx.x * 4 + w;
  int head = gwh % 3, win = gwh / 3;
  short8v q[4], k[4];
  #pragma unroll
  for (int mt = 0; mt < 4; mt++)
    q[mt] = *(const short8v*)(Qg + ((size_t)gwh * 64 + mt * 16 + lo) * 32 + ig * 8);
  #pragma unroll
  for (int nt = 0; nt < 4; nt++)
    k[nt] = *(const short8v*)(Kg + ((size_t)gwh * 64 + nt * 16 + lo) * 32 + ig * 8);
  float4v s[4][4];
  #pragma unroll
  for (int mt = 0; mt < 4; mt++)
    #pragma unroll
    for (int nt = 0; nt < 4; nt++)
      s[mt][nt] = __builtin_amdgcn_mfma_f32_16x16x32_bf16(q[mt], k[nt], (float4v){0.f, 0.f, 0.f, 0.f}, 0, 0, 0);
  const float* bt = Bt + head * 4096;
  #pragma unroll
  for (int mt = 0; mt < 4; mt++) {
    #pragma unroll
    for (int r = 0; r < 4; r++) {
      int tok = mt * 16 + ig * 4 + r;
      float v[4];
      float mx = -1e30f;
      #pragma unroll
      for (int nt = 0; nt < 4; nt++) {
        v[nt] = s[mt][nt][r] + bt[tok * 64 + nt * 16 + lo];
        mx = fmaxf(mx, v[nt]);
      }
      mx = fmaxf(mx, __shfl_xor(mx, 1));
      mx = fmaxf(mx, __shfl_xor(mx, 2));
      mx = fmaxf(mx, __shfl_xor(mx, 4));
      mx = fmaxf(mx, __shfl_xor(mx, 8));
      float sm = 0.f;
      #pragma unroll
      for (int nt = 0; nt < 4; nt++) { v[nt] = __expf(v[nt] - mx); sm += v[nt]; }
      sm += __shfl_xor(sm, 1);
      sm += __shfl_xor(sm, 2);
      sm += __shfl_xor(sm, 4);
      sm += __shfl_xor(sm, 8);
      float inv = 1.f / sm;
      #pragma unroll
      for (int nt = 0; nt < 4; nt++)
        Pl[w][tok][nt * 16 + lo] = (short)f2bf(v[nt] * inv);
    }
  }
  short8v pa[4][2], vb[2][2];
  #pragma unroll
  for (int mt = 0; mt < 4; mt++)
    #pragma unroll
    for (int kc = 0; kc < 2; kc++)
      pa[mt][kc] = *(const short8v*)&Pl[w][mt * 16 + lo][kc * 32 + ig * 8];
  #pragma unroll
  for (int ct = 0; ct < 2; ct++)
    #pragma unroll
    for (int kc = 0; kc < 2; kc++)
      vb[ct][kc] = *(const short8v*)(Vg + ((size_t)gwh * 32 + ct * 16 + lo) * 64 + kc * 32 + ig * 8);
  #pragma unroll
  for (int mt = 0; mt < 4; mt++)
    #pragma unroll
    for (int ct = 0; ct < 2; ct++) {
      float4v o = __builtin_amdgcn_mfma_f32_16x16x32_bf16(pa[mt][0], vb[ct][0], (float4v){0.f, 0.f, 0.f, 0.f}, 0, 0, 0);
      o = __builtin_amdgcn_mfma_f32_16x16x32_bf16(pa[mt][1], vb[ct][1], o, 0, 0, 0);
      #pragma unroll
      for (int r = 0; r < 4; r++)
        Og[((size_t)(win * 64 + mt * 16 + ig * 4 + r)) * 96 + head * 32 + ct * 16 + lo] = (short)f2bf(o[r]);
    }
}

// ---------------- proj + residual -> conv-layout bf16 ----------------
__global__ __launch_bounds__(256) void k_proj(const short* __restrict__ Og, const unsigned* __restrict__ Xg,
    const short* __restrict__ Wa, const float* __restrict__ ab, short* __restrict__ Xt) {
  int win = blockIdx.x;
  __shared__ float sOut[64][100];
  int tid = threadIdx.x;
  int w = tid >> 6, l = tid & 63, lo = l & 15, ig = l >> 4;
  int mt = w;
  short8v a[3];
  #pragma unroll
  for (int kc = 0; kc < 3; kc++)
    a[kc] = *(const short8v*)(Og + ((size_t)(win * 64 + mt * 16 + lo)) * 96 + kc * 32 + ig * 8);
  #pragma unroll
  for (int nt = 0; nt < 6; nt++) {
    float4v acc = (float4v){0.f, 0.f, 0.f, 0.f};
    #pragma unroll
    for (int kc = 0; kc < 3; kc++) {
      short8v bfr = *(const short8v*)(Wa + (size_t)(nt * 16 + lo) * 96 + kc * 32 + ig * 8);
      acc = __builtin_amdgcn_mfma_f32_16x16x32_bf16(a[kc], bfr, acc, 0, 0, 0);
    }
    int out = nt * 16 + lo;
    float bias = ab[out];
    #pragma unroll
    for (int r = 0; r < 4; r++) {
      int tok = mt * 16 + ig * 4 + r;
      unsigned u = Xg[(size_t)(win * 64 + tok) * 48 + (out >> 1)];
      sOut[tok][out] = acc[r] + bias + ((out & 1) ? bfh(u) : bfl(u));
    }
  }
  __syncthreads();
  int b = win >> 9, zb = (win >> 6) & 7, hb = (win >> 3) & 7, wb = win & 7;
  for (int id = tid; id < 3072; id += 256) {
    int cc = id >> 10, rem = id & 1023, t = rem >> 4, ilp = rem & 15;
    int d0 = cc * 32 + ilp * 2;
    unsigned pk = pk2(sOut[t][d0], sOut[t][d0 + 1]);
    int tz = t >> 4, th = (t >> 2) & 3, tw = t & 3;
    size_t vox = (size_t)(zb * 4 + tz) * 1024 + (hb * 4 + th) * 32 + wb * 4 + tw;
    ((unsigned*)Xt)[((size_t)(b * 3 + cc) * 32768 + vox) * 16 + ilp] = pk;
  }
}

// ---------------- MFMA conv 3x3x3 ----------------
__global__ __launch_bounds__(512) void k_convM(const short* __restrict__ Xt,
    const short* __restrict__ Wt, const float* __restrict__ cb, float* __restrict__ y) {
  int x = blockIdx.x;
  int b = x >> 7, z = (x >> 2) & 31, hq = x & 3;
  int tid = threadIdx.x;
  int wv = tid >> 6, l = tid & 63;
  int lo = l & 15, ig = l >> 4;
  __shared__ short Xl[32640];   // [3z][10h][34w][32i]
  float4v acc[6][2];
  #pragma unroll
  for (int m = 0; m < 6; m++)
    #pragma unroll
    for (int n = 0; n < 2; n++) acc[m][n] = (float4v){0.f, 0.f, 0.f, 0.f};

  for (int c = 0; c < 3; c++) {
    __syncthreads();
    for (int r = 0; r < 8; r++) {
      int id = tid + 512 * r;
      if (id < 4080) {
        int seg = id & 3, q = id >> 2;
        int zz = q / 340, rem = q - zz * 340;
        int hh = rem / 34, ww = rem - hh * 34;
        int gz = z + zz - 1, gh = hq * 8 + hh - 1, gw = ww - 1;
        int4 val = {0, 0, 0, 0};
        if (gz >= 0 && gz < 32 && gh >= 0 && gh < 32 && gw >= 0 && gw < 32)
          val = *(const int4*)(Xt + ((size_t)((b * 3 + c) * 32768 + (gz << 10) + (gh << 5) + gw) * 32 + seg * 8));
        *(int4*)(&Xl[q * 32 + seg * 8]) = val;
      }
    }
    __syncthreads();
    for (int tap = 0; tap < 27; tap++) {
      int dz = tap / 9, dh = (tap % 9) / 3, dwv = tap % 3;
      short8v a[6];
      #pragma unroll
      for (int m = 0; m < 6; m++)
        a[m] = *reinterpret_cast<const short8v*>(Wt + ((size_t)(tap * 96 + m * 16 + lo)) * 96 + c * 32 + ig * 8);
      #pragma unroll
      for (int n = 0; n < 2; n++) {
        int baddr = ((dz * 10 + wv + dh) * 34 + n * 16 + lo + dwv) * 32 + ig * 8;
        short8v bf = *reinterpret_cast<const short8v*>(&Xl[baddr]);
        #pragma unroll
        for (int m = 0; m < 6; m++)
          acc[m][n] = __builtin_amdgcn_mfma_f32_16x16x32_bf16(a[m], bf, acc[m][n], 0, 0, 0);
      }
    }
  }
  int h = hq * 8 + wv;
  #pragma unroll
  for (int m = 0; m < 6; m++)
    #pragma unroll
    for (int n = 0; n < 2; n++)
      #pragma unroll
      for (int r = 0; r < 4; r++) {
        int o = m * 16 + ig * 4 + r;
        int vcol = n * 16 + lo;
        y[((size_t)(b * 96 + o) << 15) + (z << 10) + (h << 5) + vcol] = acc[m][n][r] + cb[o];
      }
}

// ---------------- GN stats ----------------
__global__ __launch_bounds__(256) void k_stats(const float* __restrict__ y, float* __restrict__ stats) {
  int x = blockIdx.x;
  int bo = x >> 4, seg = x & 15;
  int b = bo / 96, o = bo % 96;
  const float* p = y + (size_t)bo * 32768 + seg * 2048;
  int tid = threadIdx.x;
  float s = 0.f, ss = 0.f;
  #pragma unroll
  for (int r = 0; r < 2; r++) {
    float4 v = ((const float4*)p)[tid + 256 * r];
    s += v.x + v.y + v.z + v.w;
    ss += v.x * v.x + v.y * v.y + v.z * v.z + v.w * v.w;
  }
  __shared__ float rs[256], rss[256];
  rs[tid] = s; rss[tid] = ss;
  __syncthreads();
  for (int st = 128; st > 0; st >>= 1) {
    if (tid < st) { rs[tid] += rs[tid + st]; rss[tid] += rss[tid + st]; }
    __syncthreads();
  }
  if (tid == 0) {
    int g = b * 8 + o / 12;
    atomicAdd(&stats[2 * g], rs[0]);
    atomicAdd(&stats[2 * g + 1], rss[0]);
  }
}

// ---------------- GN apply + GELU -> bf16 conv layout ----------------
__global__ __launch_bounds__(256) void k_gn(const float* __restrict__ y, const float* __restrict__ stats,
    const float* __restrict__ gg, const float* __restrict__ gb, short* __restrict__ xt) {
  int x = blockIdx.x;
  int b = x / 1536, r = x % 1536, c = r / 512, vt = r % 512;
  int v0 = vt * 64;
  __shared__ float sT[64][33];
  int tid = threadIdx.x;
  const float invN = 1.f / 393216.f;
  for (int id = tid; id < 2048; id += 256) {
    int ol = id >> 6, v = id & 63;
    int o = c * 32 + ol, g = b * 8 + o / 12;
    float m = stats[2 * g] * invN;
    float var = stats[2 * g + 1] * invN - m * m;
    float val = (y[((size_t)(b * 96 + o) << 15) + v0 + v] - m) * rsqrtf(var + 1e-5f) * gg[o] + gb[o];
    sT[v][ol] = 0.5f * val * (1.f + erff(val * 0.70710678118654752f));
  }
  __syncthreads();
  for (int id = tid; id < 1024; id += 256) {
    int v = id >> 4, p = id & 15;
    ((unsigned*)xt)[((size_t)(b * 3 + c) * 32768 + v0 + v) * 16 + p] = pk2(sT[v][2 * p], sT[v][2 * p + 1]);
  }
}

// ---------------- reconstruct (MFMA) + baseline z-interp ----------------
// A = f5b bf16 [vox][96] (direct from global), B = Wrec bf16 [j=128][i=96]
__global__ __launch_bounds__(256) void k_final(const short* __restrict__ f5b, const float* __restrict__ sp,
    const short* __restrict__ Wrec, const float* __restrict__ rb, const int* __restrict__ T,
    float* __restrict__ out) {
  int x = blockIdx.x;
  int b = x >> 10, chunk = x & 1023;
  int z = chunk >> 5, h = chunk & 31;
  int v0 = chunk * 32;
  int tid = threadIdx.x;
  int w = tid >> 6, l = tid & 63, lo = l & 15, ig = l >> 4;
  short8v afrag[2][3];
  #pragma unroll
  for (int mt = 0; mt < 2; mt++)
    #pragma unroll
    for (int kc = 0; kc < 3; kc++)
      afrag[mt][kc] = *(const short8v*)(f5b +
          ((size_t)(b * 3 + kc) * 32768 + v0 + mt * 16 + lo) * 32 + ig * 8);
  float4v acc[2][2];
  #pragma unroll
  for (int nt2 = 0; nt2 < 2; nt2++) {
    int jt = w * 2 + nt2;
    #pragma unroll
    for (int mt = 0; mt < 2; mt++) acc[mt][nt2] = (float4v){0.f, 0.f, 0.f, 0.f};
    #pragma unroll
    for (int kc = 0; kc < 3; kc++) {
      short8v bfr = *(const short8v*)(Wrec + (size_t)(jt * 16 + lo) * 96 + kc * 32 + ig * 8);
      #pragma unroll
      for (int mt = 0; mt < 2; mt++)
        acc[mt][nt2] = __builtin_amdgcn_mfma_f32_16x16x32_bf16(afrag[mt][kc], bfr, acc[mt][nt2], 0, 0, 0);
    }
  }
  const float* w64 = (const float*)(T + 128);
  #pragma unroll
  for (int mt = 0; mt < 2; mt++)
    #pragma unroll
    for (int nt2 = 0; nt2 < 2; nt2++) {
      int jt = w * 2 + nt2;
      #pragma unroll
      for (int r = 0; r < 4; r++) {
        int wv = mt * 16 + ig * 4 + r;   // voxel w-coordinate (v0 + wv, and v0%32==0)
        int j = jt * 16 + lo;
        int o = j >> 5, dd = (j >> 4) & 1, e = (j >> 2) & 3, ff = j & 3;
        int Z = 2 * z + dd, H = 4 * h + e, W = 4 * wv + ff;
        int zl = T[Z], zr = T[64 + Z];
        float bw = w64[Z];
        const float* spb = sp + (size_t)(b * 4 + o) * 196608;
        float bval = (1.f - bw) * spb[(size_t)zl * 16384 + H * 128 + W]
                   + bw * spb[(size_t)zr * 16384 + H * 128 + W];
        out[((size_t)(b * 4 + o) * 64 + Z) * 16384 + H * 128 + W] = bval + acc[mt][nt2][r] + rb[o];
      }
    }
}

extern "C" void kernel_launch(void* const* d_in, const int* in_sizes, int n_in,
                              void* d_out, int out_size, void* d_ws, size_t ws_size,
                              hipStream_t stream) {
  const float* sp    = (const float*)d_in[0];
  const float* ef    = (const float*)d_in[1];
  const float* pe_w  = (const float*)d_in[2];
  const float* pe_b  = (const float*)d_in[3];
  const float* pe_g  = (const float*)d_in[4];
  const float* pe_be = (const float*)d_in[5];
  const float* enc_w = (const float*)d_in[6];
  const float* enc_b = (const float*)d_in[7];
  const float* ln_g  = (const float*)d_in[8];
  const float* ln_b  = (const float*)d_in[9];
  const float* qkv_w = (const float*)d_in[10];
  const float* qkv_b = (const float*)d_in[11];
  const float* at_w  = (const float*)d_in[12];
  const float* at_b  = (const float*)d_in[13];
  const float* rpb   = (const float*)d_in[14];
  const float* w1    = (const float*)d_in[15];
  const float* b1    = (const float*)d_in[16];
  const float* g1g   = (const float*)d_in[17];
  const float* g1b   = (const float*)d_in[18];
  const float* w2    = (const float*)d_in[19];
  const float* b2    = (const float*)d_in[20];
  const float* g2g   = (const float*)d_in[21];
  const float* g2b   = (const float*)d_in[22];
  const float* recw  = (const float*)d_in[23];
  const float* recb  = (const float*)d_in[24];
  const int*   sidx  = (const int*)d_in[25];
  float* out = (float*)d_out;

  char* ws = (char*)d_ws;
  unsigned* Xg = (unsigned*)ws;                    // X bf16-pairs [131072][48]
  float* f1    = (float*)(ws + 25165824);
  short* Qg    = (short*)(ws + 25165824);
  short* Kg    = (short*)(ws + 50331648);
  short* Vg    = (short*)(ws + 75497472);
  short* XtA   = (short*)(ws + 25165824);
  float* Y     = (float*)(ws + 50331648);
  int*   T     = (int*)(ws + 100663296);
  float* stats = (float*)(ws + 100665344);
  short* Wrec  = (short*)(ws + 100666368);         // read by k_final (can't live in d_out)

  char* dob = (char*)d_out;
  short* Og   = (short*)d_out;                     // dead space until k_final
  short* Wenc = (short*)(dob + 25165824);
  short* Wpe  = (short*)(dob + 25184256);
  short* Wqkv = (short*)(dob + 65937408);
  short* Waw  = (short*)(dob + 65992704);
  float* Bt   = (float*)(dob + 66011136);
  short* Wt1  = (short*)(dob + 66060288);
  short* Wt2  = (short*)(dob + 66557952);

  k_tables<<<1, 96, 0, stream>>>(sidx, T);
  k_wcv<<<972, 256, 0, stream>>>(w1, Wt1);
  k_wcv<<<972, 256, 0, stream>>>(w2, Wt2);
  k_cvt<<<108, 256, 0, stream>>>(qkv_w, Wqkv, 27648);
  k_cvt<<<36, 256, 0, stream>>>(at_w, Waw, 9216);
  k_cvt<<<36, 256, 0, stream>>>(enc_w, Wenc, 9216);
  k_cvt<<<24, 256, 0, stream>>>(pe_w, Wpe, 6144);
  k_wrt<<<48, 256, 0, stream>>>(recw, Wrec);
  k_bias<<<48, 256, 0, stream>>>(rpb, Bt);

  k_pe<<<1536, 256, 0, stream>>>(sp, Wpe, pe_b, pe_g, pe_be, f1);
  k_ie<<<2048, 256, 0, stream>>>(f1, ef, Wenc, enc_b, T, Xg);
  k_qkv<<<2048, 512, 0, stream>>>(Xg, Wqkv, qkv_b, ln_g, ln_b, Qg, Kg, Vg);
  k_att2<<<1536, 256, 0, stream>>>(Qg, Kg, Vg, Bt, Og);
  k_proj<<<2048, 256, 0, stream>>>(Og, Xg, Waw, at_b, XtA);

  k_convM<<<512, 512, 0, stream>>>(XtA, Wt1, b1, Y);
  hipMemsetAsync(stats, 0, 64 * sizeof(float), stream);
  k_stats<<<6144, 256, 0, stream>>>(Y, stats);
  k_gn<<<6144, 256, 0, stream>>>(Y, stats, g1g, g1b, XtA);

  k_convM<<<512, 512, 0, stream>>>(XtA, Wt2, b2, Y);
  hipMemsetAsync(stats, 0, 64 * sizeof(float), stream);
  k_stats<<<6144, 256, 0, stream>>>(Y, stats);
  k_gn<<<6144, 256, 0, stream>>>(Y, stats, g2g, g2b, XtA);

  k_final<<<4096, 256, 0, stream>>>(XtA, sp, Wrec, recb, T, out);
}

// Round 5
// 598.494 us; speedup vs baseline: 24.5665x; 1.1472x over previous
//
#include <hip/hip_runtime.h>
#include <math.h>

typedef __attribute__((ext_vector_type(8))) short short8v;
typedef __attribute__((ext_vector_type(4))) float float4v;

__device__ inline unsigned short f2bf(float f) {
  unsigned u = __float_as_uint(f);
  return (unsigned short)((u + 0x7fff + ((u >> 16) & 1)) >> 16);
}
__device__ inline unsigned pk2(float a, float b) {
  return (unsigned)f2bf(a) | ((unsigned)f2bf(b) << 16);
}
__device__ inline float bfl(unsigned u) { return __uint_as_float(u << 16); }
__device__ inline float bfh(unsigned u) { return __uint_as_float(u & 0xffff0000u); }
__device__ inline float bfs(short s) { return __uint_as_float(((unsigned)(unsigned short)s) << 16); }

// ---------------- tables ----------------
__global__ __launch_bounds__(96) void k_tables(const int* __restrict__ sidx, int* __restrict__ T) {
  __shared__ float pos[12];
  int t = threadIdx.x;
  if (t < 12) pos[t] = (float)sidx[t];
  __syncthreads();
  if (t < 64) {
    float zq = (float)t;
    int r = 0;
    while (r < 12 && pos[r] < zq) r++;
    int l = r - 1; if (l < 0) l = 0; if (l > 11) l = 11;
    int rc = r; if (rc > 11) rc = 11;
    float lp = pos[l], rp = pos[rc], d = rp - lp;
    float w = d > 0.f ? (zq - lp) / d : 0.5f;
    T[t] = l; T[64 + t] = rc; ((float*)T)[128 + t] = w;
  } else {
    int zq = t - 64;
    float zqf = (float)zq;
    int r = 0;
    while (r < 12 && pos[r] * 0.5f < zqf) r++;
    int l = r - 1; if (l < 0) l = 0; if (l > 11) l = 11;
    int rc = r; if (rc > 11) rc = 11;
    float lp = pos[l] * 0.5f, rp = pos[rc] * 0.5f, d = rp - lp;
    float w = d > 0.f ? (zqf - lp) / d : 0.5f;
    T[192 + zq] = l; T[224 + zq] = rc; ((float*)T)[256 + zq] = w;
  }
}

// ---------------- conv weight convert: [o][i][27] f32 -> [tap][o][i] bf16 ----------------
__global__ __launch_bounds__(256) void k_wcv(const float* __restrict__ w, short* __restrict__ Wt) {
  int id = blockIdx.x * 256 + threadIdx.x;
  if (id >= 248832) return;
  float v = w[id];
  int o = id / 2592; int rem = id % 2592; int i = rem / 27; int tap = rem % 27;
  Wt[(tap * 96 + o) * 96 + i] = (short)f2bf(v);
}

// ---------------- generic f32 -> bf16 ----------------
__global__ __launch_bounds__(256) void k_cvt(const float* __restrict__ src, short* __restrict__ dst, int n) {
  int id = blockIdx.x * 256 + threadIdx.x;
  if (id < n) dst[id] = (short)f2bf(src[id]);
}

// ---------------- rec_w [i=96][j=128] f32 -> [j][i] bf16 ----------------
__global__ __launch_bounds__(256) void k_wrt(const float* __restrict__ src, short* __restrict__ dst) {
  int id = blockIdx.x * 256 + threadIdx.x;
  if (id >= 12288) return;
  int i = id >> 7, j = id & 127;
  dst[j * 96 + i] = (short)f2bf(src[id]);
}

// ---------------- expand rel-pos bias: Bt[head][n][m] ----------------
__global__ __launch_bounds__(256) void k_bias(const float* __restrict__ rpb, float* __restrict__ Bt) {
  int id = blockIdx.x * 256 + threadIdx.x;
  if (id >= 12288) return;
  int head = id >> 12, rem = id & 4095, n = rem >> 6, m = rem & 63;
  int dz = (n >> 4) - (m >> 4), dh = ((n >> 2) & 3) - ((m >> 2) & 3), dw = (n & 3) - (m & 3);
  Bt[id] = rpb[((dz + 3) * 49 + (dh + 3) * 7 + (dw + 3)) * 3 + head];
}

// ---------------- patch embed (MFMA) + LayerNorm ----------------
__global__ __launch_bounds__(256) void k_pe(const float* __restrict__ sp, const short* __restrict__ Wpe,
    const float* __restrict__ pb, const float* __restrict__ pg, const float* __restrict__ pbeta,
    float* __restrict__ f1) {
  int x = blockIdx.x;
  int b = x / 384, z = (x / 32) % 12, h = x % 32;
  __shared__ short sB[32][72];
  __shared__ float sF[32][97];
  __shared__ float sM[32], sR[32];
  int tid = threadIdx.x;
  for (int id = tid; id < 2048; id += 256) {
    int c = id >> 9, p = (id >> 7) & 3, col = id & 127;
    float v = sp[(((b * 4 + c) * 12 + z) * 128 + h * 4 + p) * 128 + col];
    sB[col >> 2][c * 16 + p * 4 + (col & 3)] = (short)f2bf(v);
  }
  __syncthreads();
  int w = tid >> 6, l = tid & 63, lo = l & 15, ig = l >> 4;
  int nt = w & 1, mbase = (w >> 1) * 3;
  short8v bfrag[2];
  #pragma unroll
  for (int kc = 0; kc < 2; kc++)
    bfrag[kc] = *(const short8v*)&sB[nt * 16 + lo][kc * 32 + ig * 8];
  #pragma unroll
  for (int mi = 0; mi < 3; mi++) {
    int m = mbase + mi;
    float4v acc = (float4v){0.f, 0.f, 0.f, 0.f};
    #pragma unroll
    for (int kc = 0; kc < 2; kc++) {
      short8v a = *(const short8v*)(Wpe + (size_t)(m * 16 + lo) * 64 + kc * 32 + ig * 8);
      acc = __builtin_amdgcn_mfma_f32_16x16x32_bf16(a, bfrag[kc], acc, 0, 0, 0);
    }
    int wcoord = nt * 16 + lo;
    #pragma unroll
    for (int r = 0; r < 4; r++) {
      int d = m * 16 + ig * 4 + r;
      sF[wcoord][d] = acc[r] + pb[d];
    }
  }
  __syncthreads();
  if (tid < 32) {
    int wv = tid;
    float s = 0.f, ss = 0.f;
    for (int d = 0; d < 96; d++) { float v = sF[wv][d]; s += v; ss += v * v; }
    float m = s * (1.f / 96.f);
    float var = ss * (1.f / 96.f) - m * m;
    sM[wv] = m; sR[wv] = rsqrtf(var + 1e-5f);
  }
  __syncthreads();
  for (int id = tid; id < 3072; id += 256) {
    int d = id >> 5, wv = id & 31;
    float v = (sF[wv][d] - sM[wv]) * sR[wv] * pg[d] + pbeta[d];
    f1[(((b * 96 + d) * 12 + z) * 32 + h) * 32 + wv] = v;
  }
}

// ---------------- z-interp + encoder proj (MFMA) -> X token-major bf16 ----------------
__global__ __launch_bounds__(256) void k_ie(const float* __restrict__ f1, const float* __restrict__ ef,
    const short* __restrict__ Wenc, const float* __restrict__ eb, const int* __restrict__ T,
    unsigned* __restrict__ Xg) {
  int x = blockIdx.x;
  int b = x >> 9, chunk = x & 511;
  int v0 = chunk * 64;
  int z = v0 >> 10, rp = v0 & 1023;
  int zl = T[192 + z], zr = T[224 + z];
  float wt = ((const float*)T)[256 + z];
  __shared__ short sEb[64][104];
  int tid = threadIdx.x;
  for (int id = tid; id < 6144; id += 256) {
    int c = id >> 6, vs = id & 63;
    sEb[vs][c] = (short)f2bf(ef[(size_t)(b * 96 + c) * 32768 + v0 + vs]);
  }
  __syncthreads();
  int w = tid >> 6, l = tid & 63, lo = l & 15, ig = l >> 4;
  int vcol = w * 16 + lo;
  short8v bfrag[3];
  #pragma unroll
  for (int kc = 0; kc < 3; kc++)
    bfrag[kc] = *(const short8v*)&sEb[vcol][kc * 32 + ig * 8];
  float4v acc[6];
  #pragma unroll
  for (int m = 0; m < 6; m++) {
    acc[m] = (float4v){0.f, 0.f, 0.f, 0.f};
    #pragma unroll
    for (int kc = 0; kc < 3; kc++) {
      short8v a = *(const short8v*)(Wenc + (size_t)(m * 16 + lo) * 96 + kc * 32 + ig * 8);
      acc[m] = __builtin_amdgcn_mfma_f32_16x16x32_bf16(a, bfrag[kc], acc[m], 0, 0, 0);
    }
  }
  int zb = z >> 2, tz = z & 3;
  int h0 = (chunk & 15) * 2;
  int h = h0 + (vcol >> 5), wc = vcol & 31;
  int win = ((b * 8 + zb) * 8 + (h >> 2)) * 8 + (wc >> 2);
  int t = tz * 16 + (h & 3) * 4 + (wc & 3);
  size_t xbase = (size_t)(win * 64 + t) * 48;
  float wl = 1.f - wt;
  #pragma unroll
  for (int m = 0; m < 6; m++) {
    #pragma unroll
    for (int rr = 0; rr < 2; rr++) {
      int d0 = m * 16 + ig * 4 + rr * 2;
      const float* p1a = f1 + ((size_t)(b * 96 + d0) * 12 + zl) * 1024 + rp + vcol;
      const float* p2a = f1 + ((size_t)(b * 96 + d0) * 12 + zr) * 1024 + rp + vcol;
      const float* p1b = f1 + ((size_t)(b * 96 + d0 + 1) * 12 + zl) * 1024 + rp + vcol;
      const float* p2b = f1 + ((size_t)(b * 96 + d0 + 1) * 12 + zr) * 1024 + rp + vcol;
      float va = acc[m][rr * 2] + eb[d0] + wl * p1a[0] + wt * p2a[0];
      float vb = acc[m][rr * 2 + 1] + eb[d0 + 1] + wl * p1b[0] + wt * p2b[0];
      Xg[xbase + m * 8 + ig * 2 + rr] = pk2(va, vb);
    }
  }
}

// ---------------- LN + QKV projection (MFMA) ----------------
__global__ __launch_bounds__(512) void k_qkv(const unsigned* __restrict__ Xg, const short* __restrict__ Wq,
    const float* __restrict__ qb, const float* __restrict__ lg, const float* __restrict__ lb,
    short* __restrict__ Qg, short* __restrict__ Kg, short* __restrict__ Vg) {
  int win = blockIdx.x;
  __shared__ short sX[64][104];
  __shared__ short sVt[96][72];
  __shared__ float sM[64], sRr[64];
  int tid = threadIdx.x;
  for (int id = tid; id < 3072; id += 512) {
    int row = id / 48, c2 = id % 48;
    *(unsigned*)&sX[row][c2 * 2] = Xg[(size_t)(win * 64 + row) * 48 + c2];
  }
  __syncthreads();
  {
    int token = tid >> 3, j = tid & 7;
    float s = 0.f, ss = 0.f;
    #pragma unroll
    for (int i = 0; i < 12; i++) {
      float v = bfs(sX[token][j * 12 + i]);
      s += v; ss += v * v;
    }
    s += __shfl_xor(s, 1); ss += __shfl_xor(ss, 1);
    s += __shfl_xor(s, 2); ss += __shfl_xor(ss, 2);
    s += __shfl_xor(s, 4); ss += __shfl_xor(ss, 4);
    if (j == 0) {
      float m = s * (1.f / 96.f);
      sM[token] = m;
      sRr[token] = rsqrtf(ss * (1.f / 96.f) - m * m + 1e-5f);
    }
  }
  __syncthreads();
  for (int id = tid; id < 3072; id += 512) {
    int row = id / 48, c2 = id % 48;
    unsigned u = *(unsigned*)&sX[row][c2 * 2];
    float m = sM[row], r = sRr[row];
    float v0 = (bfl(u) - m) * r * lg[2 * c2] + lb[2 * c2];
    float v1 = (bfh(u) - m) * r * lg[2 * c2 + 1] + lb[2 * c2 + 1];
    *(unsigned*)&sX[row][c2 * 2] = pk2(v0, v1);
  }
  __syncthreads();
  int w = tid >> 6, l = tid & 63, lo = l & 15, ig = l >> 4;
  int mt2 = w >> 1, nh = w & 1;
  short8v a[3];
  #pragma unroll
  for (int kc = 0; kc < 3; kc++)
    a[kc] = *(const short8v*)&sX[mt2 * 16 + lo][kc * 32 + ig * 8];
  for (int nt = nh * 9; nt < nh * 9 + 9; nt++) {
    float4v acc = (float4v){0.f, 0.f, 0.f, 0.f};
    #pragma unroll
    for (int kc = 0; kc < 3; kc++) {
      short8v bfr = *(const short8v*)(Wq + (size_t)(nt * 16 + lo) * 96 + kc * 32 + ig * 8);
      acc = __builtin_amdgcn_mfma_f32_16x16x32_bf16(a[kc], bfr, acc, 0, 0, 0);
    }
    int out = nt * 16 + lo;
    float bias = qb[out];
    if (nt < 6) {
      int head = out >> 5, c = out & 31;
      #pragma unroll
      for (int r = 0; r < 4; r++)
        Qg[((size_t)(win * 3 + head) * 64 + mt2 * 16 + ig * 4 + r) * 32 + c] =
            (short)f2bf((acc[r] + bias) * 0.17677669529663687f);
    } else if (nt < 12) {
      int o2 = out - 96, head = o2 >> 5, c = o2 & 31;
      #pragma unroll
      for (int r = 0; r < 4; r++)
        Kg[((size_t)(win * 3 + head) * 64 + mt2 * 16 + ig * 4 + r) * 32 + c] = (short)f2bf(acc[r] + bias);
    } else {
      int o2 = out - 192;
      #pragma unroll
      for (int r = 0; r < 4; r++)
        sVt[o2][mt2 * 16 + ig * 4 + r] = (short)f2bf(acc[r] + bias);
    }
  }
  __syncthreads();
  for (int id = tid; id < 768; id += 512) {
    int row = id >> 3, ch = id & 7;
    short8v v = *(short8v*)&sVt[row][ch * 8];
    *(short8v*)(Vg + ((size_t)(win * 3 + (row >> 5)) * 32 + (row & 31)) * 64 + ch * 8) = v;
  }
}

// ---------------- attention core: 1 wave = 1 window-head ----------------
__global__ __launch_bounds__(256) void k_att2(const short* __restrict__ Qg, const short* __restrict__ Kg,
    const short* __restrict__ Vg, const float* __restrict__ Bt, short* __restrict__ Og) {
  __shared__ short Pl[4][64][72];
  int tid = threadIdx.x;
  int w = tid >> 6, l = tid & 63, lo = l & 15, ig = l >> 4;
  int gwh = blockIdx.x * 4 + w;
  int head = gwh % 3, win = gwh / 3;
  short8v q[4], k[4];
  #pragma unroll
  for (int mt = 0; mt < 4; mt++)
    q[mt] = *(const short8v*)(Qg + ((size_t)gwh * 64 + mt * 16 + lo) * 32 + ig * 8);
  #pragma unroll
  for (int nt = 0; nt < 4; nt++)
    k[nt] = *(const short8v*)(Kg + ((size_t)gwh * 64 + nt * 16 + lo) * 32 + ig * 8);
  float4v s[4][4];
  #pragma unroll
  for (int mt = 0; mt < 4; mt++)
    #pragma unroll
    for (int nt = 0; nt < 4; nt++)
      s[mt][nt] = __builtin_amdgcn_mfma_f32_16x16x32_bf16(q[mt], k[nt], (float4v){0.f, 0.f, 0.f, 0.f}, 0, 0, 0);
  const float* bt = Bt + head * 4096;
  #pragma unroll
  for (int mt = 0; mt < 4; mt++) {
    #pragma unroll
    for (int r = 0; r < 4; r++) {
      int tok = mt * 16 + ig * 4 + r;
      float v[4];
      float mx = -1e30f;
      #pragma unroll
      for (int nt = 0; nt < 4; nt++) {
        v[nt] = s[mt][nt][r] + bt[tok * 64 + nt * 16 + lo];
        mx = fmaxf(mx, v[nt]);
      }
      mx = fmaxf(mx, __shfl_xor(mx, 1));
      mx = fmaxf(mx, __shfl_xor(mx, 2));
      mx = fmaxf(mx, __shfl_xor(mx, 4));
      mx = fmaxf(mx, __shfl_xor(mx, 8));
      float sm = 0.f;
      #pragma unroll
      for (int nt = 0; nt < 4; nt++) { v[nt] = __expf(v[nt] - mx); sm += v[nt]; }
      sm += __shfl_xor(sm, 1);
      sm += __shfl_xor(sm, 2);
      sm += __shfl_xor(sm, 4);
      sm += __shfl_xor(sm, 8);
      float inv = 1.f / sm;
      #pragma unroll
      for (int nt = 0; nt < 4; nt++)
        Pl[w][tok][nt * 16 + lo] = (short)f2bf(v[nt] * inv);
    }
  }
  short8v pa[4][2], vb[2][2];
  #pragma unroll
  for (int mt = 0; mt < 4; mt++)
    #pragma unroll
    for (int kc = 0; kc < 2; kc++)
      pa[mt][kc] = *(const short8v*)&Pl[w][mt * 16 + lo][kc * 32 + ig * 8];
  #pragma unroll
  for (int ct = 0; ct < 2; ct++)
    #pragma unroll
    for (int kc = 0; kc < 2; kc++)
      vb[ct][kc] = *(const short8v*)(Vg + ((size_t)gwh * 32 + ct * 16 + lo) * 64 + kc * 32 + ig * 8);
  #pragma unroll
  for (int mt = 0; mt < 4; mt++)
    #pragma unroll
    for (int ct = 0; ct < 2; ct++) {
      float4v o = __builtin_amdgcn_mfma_f32_16x16x32_bf16(pa[mt][0], vb[ct][0], (float4v){0.f, 0.f, 0.f, 0.f}, 0, 0, 0);
      o = __builtin_amdgcn_mfma_f32_16x16x32_bf16(pa[mt][1], vb[ct][1], o, 0, 0, 0);
      #pragma unroll
      for (int r = 0; r < 4; r++)
        Og[((size_t)(win * 64 + mt * 16 + ig * 4 + r)) * 96 + head * 32 + ct * 16 + lo] = (short)f2bf(o[r]);
    }
}

// ---------------- proj + residual -> conv-layout bf16 ----------------
__global__ __launch_bounds__(256) void k_proj(const short* __restrict__ Og, const unsigned* __restrict__ Xg,
    const short* __restrict__ Wa, const float* __restrict__ ab, short* __restrict__ Xt) {
  int win = blockIdx.x;
  __shared__ float sOut[64][100];
  int tid = threadIdx.x;
  int w = tid >> 6, l = tid & 63, lo = l & 15, ig = l >> 4;
  int mt = w;
  short8v a[3];
  #pragma unroll
  for (int kc = 0; kc < 3; kc++)
    a[kc] = *(const short8v*)(Og + ((size_t)(win * 64 + mt * 16 + lo)) * 96 + kc * 32 + ig * 8);
  #pragma unroll
  for (int nt = 0; nt < 6; nt++) {
    float4v acc = (float4v){0.f, 0.f, 0.f, 0.f};
    #pragma unroll
    for (int kc = 0; kc < 3; kc++) {
      short8v bfr = *(const short8v*)(Wa + (size_t)(nt * 16 + lo) * 96 + kc * 32 + ig * 8);
      acc = __builtin_amdgcn_mfma_f32_16x16x32_bf16(a[kc], bfr, acc, 0, 0, 0);
    }
    int out = nt * 16 + lo;
    float bias = ab[out];
    #pragma unroll
    for (int r = 0; r < 4; r++) {
      int tok = mt * 16 + ig * 4 + r;
      unsigned u = Xg[(size_t)(win * 64 + tok) * 48 + (out >> 1)];
      sOut[tok][out] = acc[r] + bias + ((out & 1) ? bfh(u) : bfl(u));
    }
  }
  __syncthreads();
  int b = win >> 9, zb = (win >> 6) & 7, hb = (win >> 3) & 7, wb = win & 7;
  for (int id = tid; id < 3072; id += 256) {
    int cc = id >> 10, rem = id & 1023, t = rem >> 4, ilp = rem & 15;
    int d0 = cc * 32 + ilp * 2;
    unsigned pk = pk2(sOut[t][d0], sOut[t][d0 + 1]);
    int tz = t >> 4, th = (t >> 2) & 3, tw = t & 3;
    size_t vox = (size_t)(zb * 4 + tz) * 1024 + (hb * 4 + th) * 32 + wb * 4 + tw;
    ((unsigned*)Xt)[((size_t)(b * 3 + cc) * 32768 + vox) * 16 + ilp] = pk;
  }
}

// ---------------- MFMA conv 3x3x3: [2z][8h][32w] tile, padded LDS, weight pipeline ----------------
#define CONV_TAP(WREG, TAP) { \
  int dz = (TAP) / 9, dh = ((TAP) % 9) / 3, dwv = (TAP) % 3; \
  short8v bf[2][2]; \
  _Pragma("unroll") \
  for (int zo = 0; zo < 2; zo++) \
    _Pragma("unroll") \
    for (int n = 0; n < 2; n++) { \
      int vox = ((zo + dz) * 10 + wv + dh) * 34 + n * 16 + lo + dwv; \
      bf[zo][n] = *(const short8v*)&Xl[vox * 40 + ig * 8]; \
    } \
  _Pragma("unroll") \
  for (int m = 0; m < 6; m++) \
    _Pragma("unroll") \
    for (int zo = 0; zo < 2; zo++) \
      _Pragma("unroll") \
      for (int n = 0; n < 2; n++) \
        acc[m][zo][n] = __builtin_amdgcn_mfma_f32_16x16x32_bf16(WREG[m], bf[zo][n], acc[m][zo][n], 0, 0, 0); \
}

#define LOADW(WREG, TAP) { \
  _Pragma("unroll") \
  for (int m = 0; m < 6; m++) \
    WREG[m] = *(const short8v*)(Wt + ((size_t)((TAP) * 96 + m * 16 + lo)) * 96 + c * 32 + ig * 8); \
}

__global__ __launch_bounds__(512) void k_convM(const short* __restrict__ Xt,
    const short* __restrict__ Wt, const float* __restrict__ cb, float* __restrict__ y) {
  int x = blockIdx.x;
  int b = x >> 6, zp = (x >> 2) & 15, hq = x & 3;
  int tid = threadIdx.x;
  int wv = tid >> 6, l = tid & 63;
  int lo = l & 15, ig = l >> 4;
  __shared__ short Xl[54400];   // [4z][10h][34w] voxels x 40 shorts (pad 32->40)
  float4v acc[6][2][2];
  #pragma unroll
  for (int m = 0; m < 6; m++)
    #pragma unroll
    for (int zo = 0; zo < 2; zo++)
      #pragma unroll
      for (int n = 0; n < 2; n++) acc[m][zo][n] = (float4v){0.f, 0.f, 0.f, 0.f};

  for (int c = 0; c < 3; c++) {
    __syncthreads();
    // stage [zp*2-1 .. zp*2+2][hq*8-1 .. +8][w -1..32][32i] with zero pad, 5440 int4 chunks
    for (int r = 0; r < 11; r++) {
      int id = tid + 512 * r;
      if (id < 5440) {
        int seg = id & 3, q = id >> 2;
        int zz = q / 340, rem = q - zz * 340;
        int hh = rem / 34, ww = rem - hh * 34;
        int gz = zp * 2 + zz - 1, gh = hq * 8 + hh - 1, gw = ww - 1;
        int4 val = {0, 0, 0, 0};
        if (gz >= 0 && gz < 32 && gh >= 0 && gh < 32 && gw >= 0 && gw < 32)
          val = *(const int4*)(Xt + ((size_t)((b * 3 + c) * 32768 + (gz << 10) + (gh << 5) + gw) * 32 + seg * 8));
        *(int4*)(&Xl[q * 40 + seg * 8]) = val;
      }
    }
    __syncthreads();
    // 2-deep weight pipeline over 27 taps
    short8v wA[6], wB[6];
    LOADW(wA, 0);
    for (int tp = 0; tp < 13; tp++) {
      int tap = tp * 2;
      LOADW(wB, tap + 1);
      CONV_TAP(wA, tap);
      LOADW(wA, tap + 2);
      CONV_TAP(wB, tap + 1);
    }
    CONV_TAP(wA, 26);
  }
  int h = hq * 8 + wv;
  #pragma unroll
  for (int m = 0; m < 6; m++)
    #pragma unroll
    for (int zo = 0; zo < 2; zo++)
      #pragma unroll
      for (int n = 0; n < 2; n++)
        #pragma unroll
        for (int r = 0; r < 4; r++) {
          int o = m * 16 + ig * 4 + r;
          int z = zp * 2 + zo;
          int vcol = n * 16 + lo;
          y[((size_t)(b * 96 + o) << 15) + (z << 10) + (h << 5) + vcol] = acc[m][zo][n][r] + cb[o];
        }
}

// ---------------- GN stats ----------------
__global__ __launch_bounds__(256) void k_stats(const float* __restrict__ y, float* __restrict__ stats) {
  int x = blockIdx.x;
  int bo = x >> 4, seg = x & 15;
  int b = bo / 96, o = bo % 96;
  const float* p = y + (size_t)bo * 32768 + seg * 2048;
  int tid = threadIdx.x;
  float s = 0.f, ss = 0.f;
  #pragma unroll
  for (int r = 0; r < 2; r++) {
    float4 v = ((const float4*)p)[tid + 256 * r];
    s += v.x + v.y + v.z + v.w;
    ss += v.x * v.x + v.y * v.y + v.z * v.z + v.w * v.w;
  }
  __shared__ float rs[256], rss[256];
  rs[tid] = s; rss[tid] = ss;
  __syncthreads();
  for (int st = 128; st > 0; st >>= 1) {
    if (tid < st) { rs[tid] += rs[tid + st]; rss[tid] += rss[tid + st]; }
    __syncthreads();
  }
  if (tid == 0) {
    int g = b * 8 + o / 12;
    atomicAdd(&stats[2 * g], rs[0]);
    atomicAdd(&stats[2 * g + 1], rss[0]);
  }
}

// ---------------- GN apply + GELU -> bf16 conv layout ----------------
__global__ __launch_bounds__(256) void k_gn(const float* __restrict__ y, const float* __restrict__ stats,
    const float* __restrict__ gg, const float* __restrict__ gb, short* __restrict__ xt) {
  int x = blockIdx.x;
  int b = x / 1536, r = x % 1536, c = r / 512, vt = r % 512;
  int v0 = vt * 64;
  __shared__ float sT[64][33];
  int tid = threadIdx.x;
  const float invN = 1.f / 393216.f;
  for (int id = tid; id < 2048; id += 256) {
    int ol = id >> 6, v = id & 63;
    int o = c * 32 + ol, g = b * 8 + o / 12;
    float m = stats[2 * g] * invN;
    float var = stats[2 * g + 1] * invN - m * m;
    float val = (y[((size_t)(b * 96 + o) << 15) + v0 + v] - m) * rsqrtf(var + 1e-5f) * gg[o] + gb[o];
    sT[v][ol] = 0.5f * val * (1.f + erff(val * 0.70710678118654752f));
  }
  __syncthreads();
  for (int id = tid; id < 1024; id += 256) {
    int v = id >> 4, p = id & 15;
    ((unsigned*)xt)[((size_t)(b * 3 + c) * 32768 + v0 + v) * 16 + p] = pk2(sT[v][2 * p], sT[v][2 * p + 1]);
  }
}

// ---------------- reconstruct (MFMA) + baseline z-interp ----------------
__global__ __launch_bounds__(256) void k_final(const short* __restrict__ f5b, const float* __restrict__ sp,
    const short* __restrict__ Wrec, const float* __restrict__ rb, const int* __restrict__ T,
    float* __restrict__ out) {
  int x = blockIdx.x;
  int b = x >> 10, chunk = x & 1023;
  int z = chunk >> 5, h = chunk & 31;
  int v0 = chunk * 32;
  int tid = threadIdx.x;
  int w = tid >> 6, l = tid & 63, lo = l & 15, ig = l >> 4;
  short8v afrag[2][3];
  #pragma unroll
  for (int mt = 0; mt < 2; mt++)
    #pragma unroll
    for (int kc = 0; kc < 3; kc++)
      afrag[mt][kc] = *(const short8v*)(f5b +
          ((size_t)(b * 3 + kc) * 32768 + v0 + mt * 16 + lo) * 32 + ig * 8);
  float4v acc[2][2];
  #pragma unroll
  for (int nt2 = 0; nt2 < 2; nt2++) {
    int jt = w * 2 + nt2;
    #pragma unroll
    for (int mt = 0; mt < 2; mt++) acc[mt][nt2] = (float4v){0.f, 0.f, 0.f, 0.f};
    #pragma unroll
    for (int kc = 0; kc < 3; kc++) {
      short8v bfr = *(const short8v*)(Wrec + (size_t)(jt * 16 + lo) * 96 + kc * 32 + ig * 8);
      #pragma unroll
      for (int mt = 0; mt < 2; mt++)
        acc[mt][nt2] = __builtin_amdgcn_mfma_f32_16x16x32_bf16(afrag[mt][kc], bfr, acc[mt][nt2], 0, 0, 0);
    }
  }
  const float* w64 = (const float*)(T + 128);
  #pragma unroll
  for (int mt = 0; mt < 2; mt++)
    #pragma unroll
    for (int nt2 = 0; nt2 < 2; nt2++) {
      int jt = w * 2 + nt2;
      #pragma unroll
      for (int r = 0; r < 4; r++) {
        int wv = mt * 16 + ig * 4 + r;
        int j = jt * 16 + lo;
        int o = j >> 5, dd = (j >> 4) & 1, e = (j >> 2) & 3, ff = j & 3;
        int Z = 2 * z + dd, H = 4 * h + e, W = 4 * wv + ff;
        int zl = T[Z], zr = T[64 + Z];
        float bw = w64[Z];
        const float* spb = sp + (size_t)(b * 4 + o) * 196608;
        float bval = (1.f - bw) * spb[(size_t)zl * 16384 + H * 128 + W]
                   + bw * spb[(size_t)zr * 16384 + H * 128 + W];
        out[((size_t)(b * 4 + o) * 64 + Z) * 16384 + H * 128 + W] = bval + acc[mt][nt2][r] + rb[o];
      }
    }
}

extern "C" void kernel_launch(void* const* d_in, const int* in_sizes, int n_in,
                              void* d_out, int out_size, void* d_ws, size_t ws_size,
                              hipStream_t stream) {
  const float* sp    = (const float*)d_in[0];
  const float* ef    = (const float*)d_in[1];
  const float* pe_w  = (const float*)d_in[2];
  const float* pe_b  = (const float*)d_in[3];
  const float* pe_g  = (const float*)d_in[4];
  const float* pe_be = (const float*)d_in[5];
  const float* enc_w = (const float*)d_in[6];
  const float* enc_b = (const float*)d_in[7];
  const float* ln_g  = (const float*)d_in[8];
  const float* ln_b  = (const float*)d_in[9];
  const float* qkv_w = (const float*)d_in[10];
  const float* qkv_b = (const float*)d_in[11];
  const float* at_w  = (const float*)d_in[12];
  const float* at_b  = (const float*)d_in[13];
  const float* rpb   = (const float*)d_in[14];
  const float* w1    = (const float*)d_in[15];
  const float* b1    = (const float*)d_in[16];
  const float* g1g   = (const float*)d_in[17];
  const float* g1b   = (const float*)d_in[18];
  const float* w2    = (const float*)d_in[19];
  const float* b2    = (const float*)d_in[20];
  const float* g2g   = (const float*)d_in[21];
  const float* g2b   = (const float*)d_in[22];
  const float* recw  = (const float*)d_in[23];
  const float* recb  = (const float*)d_in[24];
  const int*   sidx  = (const int*)d_in[25];
  float* out = (float*)d_out;

  char* ws = (char*)d_ws;
  unsigned* Xg = (unsigned*)ws;
  float* f1    = (float*)(ws + 25165824);
  short* Qg    = (short*)(ws + 25165824);
  short* Kg    = (short*)(ws + 50331648);
  short* Vg    = (short*)(ws + 75497472);
  short* XtA   = (short*)(ws + 25165824);
  float* Y     = (float*)(ws + 50331648);
  int*   T     = (int*)(ws + 100663296);
  float* stats = (float*)(ws + 100665344);
  short* Wrec  = (short*)(ws + 100666368);

  char* dob = (char*)d_out;
  short* Og   = (short*)d_out;
  short* Wenc = (short*)(dob + 25165824);
  short* Wpe  = (short*)(dob + 25184256);
  short* Wqkv = (short*)(dob + 65937408);
  short* Waw  = (short*)(dob + 65992704);
  float* Bt   = (float*)(dob + 66011136);
  short* Wt1  = (short*)(dob + 66060288);
  short* Wt2  = (short*)(dob + 66557952);

  k_tables<<<1, 96, 0, stream>>>(sidx, T);
  k_wcv<<<972, 256, 0, stream>>>(w1, Wt1);
  k_wcv<<<972, 256, 0, stream>>>(w2, Wt2);
  k_cvt<<<108, 256, 0, stream>>>(qkv_w, Wqkv, 27648);
  k_cvt<<<36, 256, 0, stream>>>(at_w, Waw, 9216);
  k_cvt<<<36, 256, 0, stream>>>(enc_w, Wenc, 9216);
  k_cvt<<<24, 256, 0, stream>>>(pe_w, Wpe, 6144);
  k_wrt<<<48, 256, 0, stream>>>(recw, Wrec);
  k_bias<<<48, 256, 0, stream>>>(rpb, Bt);

  k_pe<<<1536, 256, 0, stream>>>(sp, Wpe, pe_b, pe_g, pe_be, f1);
  k_ie<<<2048, 256, 0, stream>>>(f1, ef, Wenc, enc_b, T, Xg);
  k_qkv<<<2048, 512, 0, stream>>>(Xg, Wqkv, qkv_b, ln_g, ln_b, Qg, Kg, Vg);
  k_att2<<<1536, 256, 0, stream>>>(Qg, Kg, Vg, Bt, Og);
  k_proj<<<2048, 256, 0, stream>>>(Og, Xg, Waw, at_b, XtA);

  k_convM<<<256, 512, 0, stream>>>(XtA, Wt1, b1, Y);
  hipMemsetAsync(stats, 0, 64 * sizeof(float), stream);
  k_stats<<<6144, 256, 0, stream>>>(Y, stats);
  k_gn<<<6144, 256, 0, stream>>>(Y, stats, g1g, g1b, XtA);

  k_convM<<<256, 512, 0, stream>>>(XtA, Wt2, b2, Y);
  hipMemsetAsync(stats, 0, 64 * sizeof(float), stream);
  k_stats<<<6144, 256, 0, stream>>>(Y, stats);
  k_gn<<<6144, 256, 0, stream>>>(Y, stats, g2g, g2b, XtA);

  k_final<<<4096, 256, 0, stream>>>(XtA, sp, Wrec, recb, T, out);
}

// Round 6
// 392.429 us; speedup vs baseline: 37.4664x; 1.5251x over previous
//
#include <hip/hip_runtime.h>
#include <math.h>

typedef __attribute__((ext_vector_type(8))) short short8v;
typedef __attribute__((ext_vector_type(4))) float float4v;

__device__ inline unsigned short f2bf(float f) {
  unsigned u = __float_as_uint(f);
  return (unsigned short)((u + 0x7fff + ((u >> 16) & 1)) >> 16);
}
__device__ inline unsigned pk2(float a, float b) {
  return (unsigned)f2bf(a) | ((unsigned)f2bf(b) << 16);
}
__device__ inline float bfl(unsigned u) { return __uint_as_float(u << 16); }
__device__ inline float bfh(unsigned u) { return __uint_as_float(u & 0xffff0000u); }
__device__ inline float bfs(short s) { return __uint_as_float(((unsigned)(unsigned short)s) << 16); }

// ---------------- tables ----------------
__global__ __launch_bounds__(96) void k_tables(const int* __restrict__ sidx, int* __restrict__ T) {
  __shared__ float pos[12];
  int t = threadIdx.x;
  if (t < 12) pos[t] = (float)sidx[t];
  __syncthreads();
  if (t < 64) {
    float zq = (float)t;
    int r = 0;
    while (r < 12 && pos[r] < zq) r++;
    int l = r - 1; if (l < 0) l = 0; if (l > 11) l = 11;
    int rc = r; if (rc > 11) rc = 11;
    float lp = pos[l], rp = pos[rc], d = rp - lp;
    float w = d > 0.f ? (zq - lp) / d : 0.5f;
    T[t] = l; T[64 + t] = rc; ((float*)T)[128 + t] = w;
  } else {
    int zq = t - 64;
    float zqf = (float)zq;
    int r = 0;
    while (r < 12 && pos[r] * 0.5f < zqf) r++;
    int l = r - 1; if (l < 0) l = 0; if (l > 11) l = 11;
    int rc = r; if (rc > 11) rc = 11;
    float lp = pos[l] * 0.5f, rp = pos[rc] * 0.5f, d = rp - lp;
    float w = d > 0.f ? (zqf - lp) / d : 0.5f;
    T[192 + zq] = l; T[224 + zq] = rc; ((float*)T)[256 + zq] = w;
  }
}

// ---------------- conv weight convert: [o][i][27] f32 -> [tap][o][i] bf16 ----------------
__global__ __launch_bounds__(256) void k_wcv(const float* __restrict__ w, short* __restrict__ Wt) {
  int id = blockIdx.x * 256 + threadIdx.x;
  if (id >= 248832) return;
  float v = w[id];
  int o = id / 2592; int rem = id % 2592; int i = rem / 27; int tap = rem % 27;
  Wt[(tap * 96 + o) * 96 + i] = (short)f2bf(v);
}

// ---------------- generic f32 -> bf16 ----------------
__global__ __launch_bounds__(256) void k_cvt(const float* __restrict__ src, short* __restrict__ dst, int n) {
  int id = blockIdx.x * 256 + threadIdx.x;
  if (id < n) dst[id] = (short)f2bf(src[id]);
}

// ---------------- rec_w [i=96][j=128] f32 -> [j][i] bf16 ----------------
__global__ __launch_bounds__(256) void k_wrt(const float* __restrict__ src, short* __restrict__ dst) {
  int id = blockIdx.x * 256 + threadIdx.x;
  if (id >= 12288) return;
  int i = id >> 7, j = id & 127;
  dst[j * 96 + i] = (short)f2bf(src[id]);
}

// ---------------- expand rel-pos bias: Bt[head][n][m] ----------------
__global__ __launch_bounds__(256) void k_bias(const float* __restrict__ rpb, float* __restrict__ Bt) {
  int id = blockIdx.x * 256 + threadIdx.x;
  if (id >= 12288) return;
  int head = id >> 12, rem = id & 4095, n = rem >> 6, m = rem & 63;
  int dz = (n >> 4) - (m >> 4), dh = ((n >> 2) & 3) - ((m >> 2) & 3), dw = (n & 3) - (m & 3);
  Bt[id] = rpb[((dz + 3) * 49 + (dh + 3) * 7 + (dw + 3)) * 3 + head];
}

// ---------------- patch embed (MFMA) + LayerNorm ----------------
__global__ __launch_bounds__(256) void k_pe(const float* __restrict__ sp, const short* __restrict__ Wpe,
    const float* __restrict__ pb, const float* __restrict__ pg, const float* __restrict__ pbeta,
    float* __restrict__ f1) {
  int x = blockIdx.x;
  int b = x / 384, z = (x / 32) % 12, h = x % 32;
  __shared__ short sB[32][72];
  __shared__ float sF[32][97];
  __shared__ float sM[32], sR[32];
  int tid = threadIdx.x;
  for (int id = tid; id < 2048; id += 256) {
    int c = id >> 9, p = (id >> 7) & 3, col = id & 127;
    float v = sp[(((b * 4 + c) * 12 + z) * 128 + h * 4 + p) * 128 + col];
    sB[col >> 2][c * 16 + p * 4 + (col & 3)] = (short)f2bf(v);
  }
  __syncthreads();
  int w = tid >> 6, l = tid & 63, lo = l & 15, ig = l >> 4;
  int nt = w & 1, mbase = (w >> 1) * 3;
  short8v bfrag[2];
  #pragma unroll
  for (int kc = 0; kc < 2; kc++)
    bfrag[kc] = *(const short8v*)&sB[nt * 16 + lo][kc * 32 + ig * 8];
  #pragma unroll
  for (int mi = 0; mi < 3; mi++) {
    int m = mbase + mi;
    float4v acc = (float4v){0.f, 0.f, 0.f, 0.f};
    #pragma unroll
    for (int kc = 0; kc < 2; kc++) {
      short8v a = *(const short8v*)(Wpe + (size_t)(m * 16 + lo) * 64 + kc * 32 + ig * 8);
      acc = __builtin_amdgcn_mfma_f32_16x16x32_bf16(a, bfrag[kc], acc, 0, 0, 0);
    }
    int wcoord = nt * 16 + lo;
    #pragma unroll
    for (int r = 0; r < 4; r++) {
      int d = m * 16 + ig * 4 + r;
      sF[wcoord][d] = acc[r] + pb[d];
    }
  }
  __syncthreads();
  if (tid < 32) {
    int wv = tid;
    float s = 0.f, ss = 0.f;
    for (int d = 0; d < 96; d++) { float v = sF[wv][d]; s += v; ss += v * v; }
    float m = s * (1.f / 96.f);
    float var = ss * (1.f / 96.f) - m * m;
    sM[wv] = m; sR[wv] = rsqrtf(var + 1e-5f);
  }
  __syncthreads();
  for (int id = tid; id < 3072; id += 256) {
    int d = id >> 5, wv = id & 31;
    float v = (sF[wv][d] - sM[wv]) * sR[wv] * pg[d] + pbeta[d];
    f1[(((b * 96 + d) * 12 + z) * 32 + h) * 32 + wv] = v;
  }
}

// ---------------- z-interp + encoder proj (MFMA) -> X token-major bf16 ----------------
__global__ __launch_bounds__(256) void k_ie(const float* __restrict__ f1, const float* __restrict__ ef,
    const short* __restrict__ Wenc, const float* __restrict__ eb, const int* __restrict__ T,
    unsigned* __restrict__ Xg) {
  int x = blockIdx.x;
  int b = x >> 9, chunk = x & 511;
  int v0 = chunk * 64;
  int z = v0 >> 10, rp = v0 & 1023;
  int zl = T[192 + z], zr = T[224 + z];
  float wt = ((const float*)T)[256 + z];
  __shared__ short sEb[64][104];
  int tid = threadIdx.x;
  for (int id = tid; id < 6144; id += 256) {
    int c = id >> 6, vs = id & 63;
    sEb[vs][c] = (short)f2bf(ef[(size_t)(b * 96 + c) * 32768 + v0 + vs]);
  }
  __syncthreads();
  int w = tid >> 6, l = tid & 63, lo = l & 15, ig = l >> 4;
  int vcol = w * 16 + lo;
  short8v bfrag[3];
  #pragma unroll
  for (int kc = 0; kc < 3; kc++)
    bfrag[kc] = *(const short8v*)&sEb[vcol][kc * 32 + ig * 8];
  float4v acc[6];
  #pragma unroll
  for (int m = 0; m < 6; m++) {
    acc[m] = (float4v){0.f, 0.f, 0.f, 0.f};
    #pragma unroll
    for (int kc = 0; kc < 3; kc++) {
      short8v a = *(const short8v*)(Wenc + (size_t)(m * 16 + lo) * 96 + kc * 32 + ig * 8);
      acc[m] = __builtin_amdgcn_mfma_f32_16x16x32_bf16(a, bfrag[kc], acc[m], 0, 0, 0);
    }
  }
  int zb = z >> 2, tz = z & 3;
  int h0 = (chunk & 15) * 2;
  int h = h0 + (vcol >> 5), wc = vcol & 31;
  int win = ((b * 8 + zb) * 8 + (h >> 2)) * 8 + (wc >> 2);
  int t = tz * 16 + (h & 3) * 4 + (wc & 3);
  size_t xbase = (size_t)(win * 64 + t) * 48;
  float wl = 1.f - wt;
  #pragma unroll
  for (int m = 0; m < 6; m++) {
    #pragma unroll
    for (int rr = 0; rr < 2; rr++) {
      int d0 = m * 16 + ig * 4 + rr * 2;
      const float* p1a = f1 + ((size_t)(b * 96 + d0) * 12 + zl) * 1024 + rp + vcol;
      const float* p2a = f1 + ((size_t)(b * 96 + d0) * 12 + zr) * 1024 + rp + vcol;
      const float* p1b = f1 + ((size_t)(b * 96 + d0 + 1) * 12 + zl) * 1024 + rp + vcol;
      const float* p2b = f1 + ((size_t)(b * 96 + d0 + 1) * 12 + zr) * 1024 + rp + vcol;
      float va = acc[m][rr * 2] + eb[d0] + wl * p1a[0] + wt * p2a[0];
      float vb = acc[m][rr * 2 + 1] + eb[d0 + 1] + wl * p1b[0] + wt * p2b[0];
      Xg[xbase + m * 8 + ig * 2 + rr] = pk2(va, vb);
    }
  }
}

// ---------------- LN + QKV projection (MFMA) ----------------
__global__ __launch_bounds__(512) void k_qkv(const unsigned* __restrict__ Xg, const short* __restrict__ Wq,
    const float* __restrict__ qb, const float* __restrict__ lg, const float* __restrict__ lb,
    short* __restrict__ Qg, short* __restrict__ Kg, short* __restrict__ Vg) {
  int win = blockIdx.x;
  __shared__ short sX[64][104];
  __shared__ short sVt[96][72];
  __shared__ float sM[64], sRr[64];
  int tid = threadIdx.x;
  for (int id = tid; id < 3072; id += 512) {
    int row = id / 48, c2 = id % 48;
    *(unsigned*)&sX[row][c2 * 2] = Xg[(size_t)(win * 64 + row) * 48 + c2];
  }
  __syncthreads();
  {
    int token = tid >> 3, j = tid & 7;
    float s = 0.f, ss = 0.f;
    #pragma unroll
    for (int i = 0; i < 12; i++) {
      float v = bfs(sX[token][j * 12 + i]);
      s += v; ss += v * v;
    }
    s += __shfl_xor(s, 1); ss += __shfl_xor(ss, 1);
    s += __shfl_xor(s, 2); ss += __shfl_xor(ss, 2);
    s += __shfl_xor(s, 4); ss += __shfl_xor(ss, 4);
    if (j == 0) {
      float m = s * (1.f / 96.f);
      sM[token] = m;
      sRr[token] = rsqrtf(ss * (1.f / 96.f) - m * m + 1e-5f);
    }
  }
  __syncthreads();
  for (int id = tid; id < 3072; id += 512) {
    int row = id / 48, c2 = id % 48;
    unsigned u = *(unsigned*)&sX[row][c2 * 2];
    float m = sM[row], r = sRr[row];
    float v0 = (bfl(u) - m) * r * lg[2 * c2] + lb[2 * c2];
    float v1 = (bfh(u) - m) * r * lg[2 * c2 + 1] + lb[2 * c2 + 1];
    *(unsigned*)&sX[row][c2 * 2] = pk2(v0, v1);
  }
  __syncthreads();
  int w = tid >> 6, l = tid & 63, lo = l & 15, ig = l >> 4;
  int mt2 = w >> 1, nh = w & 1;
  short8v a[3];
  #pragma unroll
  for (int kc = 0; kc < 3; kc++)
    a[kc] = *(const short8v*)&sX[mt2 * 16 + lo][kc * 32 + ig * 8];
  for (int nt = nh * 9; nt < nh * 9 + 9; nt++) {
    float4v acc = (float4v){0.f, 0.f, 0.f, 0.f};
    #pragma unroll
    for (int kc = 0; kc < 3; kc++) {
      short8v bfr = *(const short8v*)(Wq + (size_t)(nt * 16 + lo) * 96 + kc * 32 + ig * 8);
      acc = __builtin_amdgcn_mfma_f32_16x16x32_bf16(a[kc], bfr, acc, 0, 0, 0);
    }
    int out = nt * 16 + lo;
    float bias = qb[out];
    if (nt < 6) {
      int head = out >> 5, c = out & 31;
      #pragma unroll
      for (int r = 0; r < 4; r++)
        Qg[((size_t)(win * 3 + head) * 64 + mt2 * 16 + ig * 4 + r) * 32 + c] =
            (short)f2bf((acc[r] + bias) * 0.17677669529663687f);
    } else if (nt < 12) {
      int o2 = out - 96, head = o2 >> 5, c = o2 & 31;
      #pragma unroll
      for (int r = 0; r < 4; r++)
        Kg[((size_t)(win * 3 + head) * 64 + mt2 * 16 + ig * 4 + r) * 32 + c] = (short)f2bf(acc[r] + bias);
    } else {
      int o2 = out - 192;
      #pragma unroll
      for (int r = 0; r < 4; r++)
        sVt[o2][mt2 * 16 + ig * 4 + r] = (short)f2bf(acc[r] + bias);
    }
  }
  __syncthreads();
  for (int id = tid; id < 768; id += 512) {
    int row = id >> 3, ch = id & 7;
    short8v v = *(short8v*)&sVt[row][ch * 8];
    *(short8v*)(Vg + ((size_t)(win * 3 + (row >> 5)) * 32 + (row & 31)) * 64 + ch * 8) = v;
  }
}

// ---------------- attention core: 1 wave = 1 window-head ----------------
__global__ __launch_bounds__(256) void k_att2(const short* __restrict__ Qg, const short* __restrict__ Kg,
    const short* __restrict__ Vg, const float* __restrict__ Bt, short* __restrict__ Og) {
  __shared__ short Pl[4][64][72];
  int tid = threadIdx.x;
  int w = tid >> 6, l = tid & 63, lo = l & 15, ig = l >> 4;
  int gwh = blockIdx.x * 4 + w;
  int head = gwh % 3, win = gwh / 3;
  short8v q[4], k[4];
  #pragma unroll
  for (int mt = 0; mt < 4; mt++)
    q[mt] = *(const short8v*)(Qg + ((size_t)gwh * 64 + mt * 16 + lo) * 32 + ig * 8);
  #pragma unroll
  for (int nt = 0; nt < 4; nt++)
    k[nt] = *(const short8v*)(Kg + ((size_t)gwh * 64 + nt * 16 + lo) * 32 + ig * 8);
  float4v s[4][4];
  #pragma unroll
  for (int mt = 0; mt < 4; mt++)
    #pragma unroll
    for (int nt = 0; nt < 4; nt++)
      s[mt][nt] = __builtin_amdgcn_mfma_f32_16x16x32_bf16(q[mt], k[nt], (float4v){0.f, 0.f, 0.f, 0.f}, 0, 0, 0);
  const float* bt = Bt + head * 4096;
  #pragma unroll
  for (int mt = 0; mt < 4; mt++) {
    #pragma unroll
    for (int r = 0; r < 4; r++) {
      int tok = mt * 16 + ig * 4 + r;
      float v[4];
      float mx = -1e30f;
      #pragma unroll
      for (int nt = 0; nt < 4; nt++) {
        v[nt] = s[mt][nt][r] + bt[tok * 64 + nt * 16 + lo];
        mx = fmaxf(mx, v[nt]);
      }
      mx = fmaxf(mx, __shfl_xor(mx, 1));
      mx = fmaxf(mx, __shfl_xor(mx, 2));
      mx = fmaxf(mx, __shfl_xor(mx, 4));
      mx = fmaxf(mx, __shfl_xor(mx, 8));
      float sm = 0.f;
      #pragma unroll
      for (int nt = 0; nt < 4; nt++) { v[nt] = __expf(v[nt] - mx); sm += v[nt]; }
      sm += __shfl_xor(sm, 1);
      sm += __shfl_xor(sm, 2);
      sm += __shfl_xor(sm, 4);
      sm += __shfl_xor(sm, 8);
      float inv = 1.f / sm;
      #pragma unroll
      for (int nt = 0; nt < 4; nt++)
        Pl[w][tok][nt * 16 + lo] = (short)f2bf(v[nt] * inv);
    }
  }
  short8v pa[4][2], vb[2][2];
  #pragma unroll
  for (int mt = 0; mt < 4; mt++)
    #pragma unroll
    for (int kc = 0; kc < 2; kc++)
      pa[mt][kc] = *(const short8v*)&Pl[w][mt * 16 + lo][kc * 32 + ig * 8];
  #pragma unroll
  for (int ct = 0; ct < 2; ct++)
    #pragma unroll
    for (int kc = 0; kc < 2; kc++)
      vb[ct][kc] = *(const short8v*)(Vg + ((size_t)gwh * 32 + ct * 16 + lo) * 64 + kc * 32 + ig * 8);
  #pragma unroll
  for (int mt = 0; mt < 4; mt++)
    #pragma unroll
    for (int ct = 0; ct < 2; ct++) {
      float4v o = __builtin_amdgcn_mfma_f32_16x16x32_bf16(pa[mt][0], vb[ct][0], (float4v){0.f, 0.f, 0.f, 0.f}, 0, 0, 0);
      o = __builtin_amdgcn_mfma_f32_16x16x32_bf16(pa[mt][1], vb[ct][1], o, 0, 0, 0);
      #pragma unroll
      for (int r = 0; r < 4; r++)
        Og[((size_t)(win * 64 + mt * 16 + ig * 4 + r)) * 96 + head * 32 + ct * 16 + lo] = (short)f2bf(o[r]);
    }
}

// ---------------- proj + residual -> conv-layout bf16 ----------------
__global__ __launch_bounds__(256) void k_proj(const short* __restrict__ Og, const unsigned* __restrict__ Xg,
    const short* __restrict__ Wa, const float* __restrict__ ab, short* __restrict__ Xt) {
  int win = blockIdx.x;
  __shared__ float sOut[64][100];
  int tid = threadIdx.x;
  int w = tid >> 6, l = tid & 63, lo = l & 15, ig = l >> 4;
  int mt = w;
  short8v a[3];
  #pragma unroll
  for (int kc = 0; kc < 3; kc++)
    a[kc] = *(const short8v*)(Og + ((size_t)(win * 64 + mt * 16 + lo)) * 96 + kc * 32 + ig * 8);
  #pragma unroll
  for (int nt = 0; nt < 6; nt++) {
    float4v acc = (float4v){0.f, 0.f, 0.f, 0.f};
    #pragma unroll
    for (int kc = 0; kc < 3; kc++) {
      short8v bfr = *(const short8v*)(Wa + (size_t)(nt * 16 + lo) * 96 + kc * 32 + ig * 8);
      acc = __builtin_amdgcn_mfma_f32_16x16x32_bf16(a[kc], bfr, acc, 0, 0, 0);
    }
    int out = nt * 16 + lo;
    float bias = ab[out];
    #pragma unroll
    for (int r = 0; r < 4; r++) {
      int tok = mt * 16 + ig * 4 + r;
      unsigned u = Xg[(size_t)(win * 64 + tok) * 48 + (out >> 1)];
      sOut[tok][out] = acc[r] + bias + ((out & 1) ? bfh(u) : bfl(u));
    }
  }
  __syncthreads();
  int b = win >> 9, zb = (win >> 6) & 7, hb = (win >> 3) & 7, wb = win & 7;
  for (int id = tid; id < 3072; id += 256) {
    int cc = id >> 10, rem = id & 1023, t = rem >> 4, ilp = rem & 15;
    int d0 = cc * 32 + ilp * 2;
    unsigned pk = pk2(sOut[t][d0], sOut[t][d0 + 1]);
    int tz = t >> 4, th = (t >> 2) & 3, tw = t & 3;
    size_t vox = (size_t)(zb * 4 + tz) * 1024 + (hb * 4 + th) * 32 + wb * 4 + tw;
    ((unsigned*)Xt)[((size_t)(b * 3 + cc) * 32768 + vox) * 16 + ilp] = pk;
  }
}

// ---------------- MFMA conv 3x3x3 + fused GN stats ----------------
#define CONV_TAP(WREG, TAP) { \
  int dz = (TAP) / 9, dh = ((TAP) % 9) / 3, dwv = (TAP) % 3; \
  short8v bf[2][2]; \
  _Pragma("unroll") \
  for (int zo = 0; zo < 2; zo++) \
    _Pragma("unroll") \
    for (int n = 0; n < 2; n++) { \
      int vox = ((zo + dz) * 10 + wv + dh) * 34 + n * 16 + lo + dwv; \
      bf[zo][n] = *(const short8v*)&Xl[vox * 40 + ig * 8]; \
    } \
  _Pragma("unroll") \
  for (int m = 0; m < 6; m++) \
    _Pragma("unroll") \
    for (int zo = 0; zo < 2; zo++) \
      _Pragma("unroll") \
      for (int n = 0; n < 2; n++) \
        acc[m][zo][n] = __builtin_amdgcn_mfma_f32_16x16x32_bf16(WREG[m], bf[zo][n], acc[m][zo][n], 0, 0, 0); \
}

#define LOADW(WREG, TAP) { \
  _Pragma("unroll") \
  for (int m = 0; m < 6; m++) \
    WREG[m] = *(const short8v*)(Wt + ((size_t)((TAP) * 96 + m * 16 + lo)) * 96 + c * 32 + ig * 8); \
}

__global__ __launch_bounds__(512) void k_convM(const short* __restrict__ Xt,
    const short* __restrict__ Wt, const float* __restrict__ cb, float* __restrict__ y,
    float* __restrict__ stats) {
  int x = blockIdx.x;
  int b = x >> 6, zp = (x >> 2) & 15, hq = x & 3;
  int tid = threadIdx.x;
  int wv = tid >> 6, l = tid & 63;
  int lo = l & 15, ig = l >> 4;
  __shared__ short Xl[54400];   // [4z][10h][34w] voxels x 40 shorts (pad 32->40)
  __shared__ float sG[16];      // 8 groups x (sum, sumsq)
  if (tid < 16) sG[tid] = 0.f;
  float4v acc[6][2][2];
  #pragma unroll
  for (int m = 0; m < 6; m++)
    #pragma unroll
    for (int zo = 0; zo < 2; zo++)
      #pragma unroll
      for (int n = 0; n < 2; n++) acc[m][zo][n] = (float4v){0.f, 0.f, 0.f, 0.f};

  for (int c = 0; c < 3; c++) {
    __syncthreads();
    for (int r = 0; r < 11; r++) {
      int id = tid + 512 * r;
      if (id < 5440) {
        int seg = id & 3, q = id >> 2;
        int zz = q / 340, rem = q - zz * 340;
        int hh = rem / 34, ww = rem - hh * 34;
        int gz = zp * 2 + zz - 1, gh = hq * 8 + hh - 1, gw = ww - 1;
        int4 val = {0, 0, 0, 0};
        if (gz >= 0 && gz < 32 && gh >= 0 && gh < 32 && gw >= 0 && gw < 32)
          val = *(const int4*)(Xt + ((size_t)((b * 3 + c) * 32768 + (gz << 10) + (gh << 5) + gw) * 32 + seg * 8));
        *(int4*)(&Xl[q * 40 + seg * 8]) = val;
      }
    }
    __syncthreads();
    short8v wA[6], wB[6];
    LOADW(wA, 0);
    for (int tp = 0; tp < 13; tp++) {
      int tap = tp * 2;
      LOADW(wB, tap + 1);
      CONV_TAP(wA, tap);
      LOADW(wA, tap + 2);
      CONV_TAP(wB, tap + 1);
    }
    CONV_TAP(wA, 26);
  }
  int h = hq * 8 + wv;
  #pragma unroll
  for (int m = 0; m < 6; m++) {
    #pragma unroll
    for (int r = 0; r < 4; r++) {
      int o = m * 16 + ig * 4 + r;
      float cbo = cb[o];
      float s = 0.f, ss = 0.f;
      #pragma unroll
      for (int zo = 0; zo < 2; zo++)
        #pragma unroll
        for (int n = 0; n < 2; n++) {
          float v = acc[m][zo][n][r] + cbo;
          int z = zp * 2 + zo;
          int vcol = n * 16 + lo;
          y[((size_t)(b * 96 + o) << 15) + (z << 10) + (h << 5) + vcol] = v;
          s += v; ss += v * v;
        }
      // reduce over the 16 lo-lanes (same o for all)
      s += __shfl_xor(s, 1); ss += __shfl_xor(ss, 1);
      s += __shfl_xor(s, 2); ss += __shfl_xor(ss, 2);
      s += __shfl_xor(s, 4); ss += __shfl_xor(ss, 4);
      s += __shfl_xor(s, 8); ss += __shfl_xor(ss, 8);
      if (lo == 0) {
        int gl = o / 12;
        atomicAdd(&sG[gl * 2], s);
        atomicAdd(&sG[gl * 2 + 1], ss);
      }
    }
  }
  __syncthreads();
  if (tid < 16) atomicAdd(&stats[b * 16 + tid], sG[tid]);
}

// ---------------- GN apply + GELU -> bf16 conv layout (vectorized loads) ----------------
__global__ __launch_bounds__(256) void k_gn(const float* __restrict__ y, const float* __restrict__ stats,
    const float* __restrict__ gg, const float* __restrict__ gb, short* __restrict__ xt) {
  int x = blockIdx.x;
  int b = x / 1536, r = x % 1536, c = r / 512, vt = r % 512;
  int v0 = vt * 64;
  __shared__ float sT[64][33];
  int tid = threadIdx.x;
  const float invN = 1.f / 393216.f;
  for (int id = tid; id < 512; id += 256) {
    int ol = id >> 4, vq = id & 15;
    int o = c * 32 + ol, g = b * 8 + o / 12;
    float m = stats[2 * g] * invN;
    float var = stats[2 * g + 1] * invN - m * m;
    float rs = rsqrtf(var + 1e-5f) * gg[o];
    float bb = gb[o];
    float4 v = *(const float4*)&y[((size_t)(b * 96 + o) << 15) + v0 + vq * 4];
    float vv[4] = {v.x, v.y, v.z, v.w};
    #pragma unroll
    for (int j = 0; j < 4; j++) {
      float val = (vv[j] - m) * rs + bb;
      sT[vq * 4 + j][ol] = 0.5f * val * (1.f + erff(val * 0.70710678118654752f));
    }
  }
  __syncthreads();
  for (int id = tid; id < 1024; id += 256) {
    int v = id >> 4, p = id & 15;
    ((unsigned*)xt)[((size_t)(b * 3 + c) * 32768 + v0 + v) * 16 + p] = pk2(sT[v][2 * p], sT[v][2 * p + 1]);
  }
}

// ---------------- reconstruct (MFMA) + baseline z-interp ----------------
__global__ __launch_bounds__(256) void k_final(const short* __restrict__ f5b, const float* __restrict__ sp,
    const short* __restrict__ Wrec, const float* __restrict__ rb, const int* __restrict__ T,
    float* __restrict__ out) {
  int x = blockIdx.x;
  int b = x >> 10, chunk = x & 1023;
  int z = chunk >> 5, h = chunk & 31;
  int v0 = chunk * 32;
  int tid = threadIdx.x;
  int w = tid >> 6, l = tid & 63, lo = l & 15, ig = l >> 4;
  short8v afrag[2][3];
  #pragma unroll
  for (int mt = 0; mt < 2; mt++)
    #pragma unroll
    for (int kc = 0; kc < 3; kc++)
      afrag[mt][kc] = *(const short8v*)(f5b +
          ((size_t)(b * 3 + kc) * 32768 + v0 + mt * 16 + lo) * 32 + ig * 8);
  float4v acc[2][2];
  #pragma unroll
  for (int nt2 = 0; nt2 < 2; nt2++) {
    int jt = w * 2 + nt2;
    #pragma unroll
    for (int mt = 0; mt < 2; mt++) acc[mt][nt2] = (float4v){0.f, 0.f, 0.f, 0.f};
    #pragma unroll
    for (int kc = 0; kc < 3; kc++) {
      short8v bfr = *(const short8v*)(Wrec + (size_t)(jt * 16 + lo) * 96 + kc * 32 + ig * 8);
      #pragma unroll
      for (int mt = 0; mt < 2; mt++)
        acc[mt][nt2] = __builtin_amdgcn_mfma_f32_16x16x32_bf16(afrag[mt][kc], bfr, acc[mt][nt2], 0, 0, 0);
    }
  }
  const float* w64 = (const float*)(T + 128);
  #pragma unroll
  for (int mt = 0; mt < 2; mt++)
    #pragma unroll
    for (int nt2 = 0; nt2 < 2; nt2++) {
      int jt = w * 2 + nt2;
      #pragma unroll
      for (int r = 0; r < 4; r++) {
        int wv = mt * 16 + ig * 4 + r;
        int j = jt * 16 + lo;
        int o = j >> 5, dd = (j >> 4) & 1, e = (j >> 2) & 3, ff = j & 3;
        int Z = 2 * z + dd, H = 4 * h + e, W = 4 * wv + ff;
        int zl = T[Z], zr = T[64 + Z];
        float bw = w64[Z];
        const float* spb = sp + (size_t)(b * 4 + o) * 196608;
        float bval = (1.f - bw) * spb[(size_t)zl * 16384 + H * 128 + W]
                   + bw * spb[(size_t)zr * 16384 + H * 128 + W];
        out[((size_t)(b * 4 + o) * 64 + Z) * 16384 + H * 128 + W] = bval + acc[mt][nt2][r] + rb[o];
      }
    }
}

extern "C" void kernel_launch(void* const* d_in, const int* in_sizes, int n_in,
                              void* d_out, int out_size, void* d_ws, size_t ws_size,
                              hipStream_t stream) {
  const float* sp    = (const float*)d_in[0];
  const float* ef    = (const float*)d_in[1];
  const float* pe_w  = (const float*)d_in[2];
  const float* pe_b  = (const float*)d_in[3];
  const float* pe_g  = (const float*)d_in[4];
  const float* pe_be = (const float*)d_in[5];
  const float* enc_w = (const float*)d_in[6];
  const float* enc_b = (const float*)d_in[7];
  const float* ln_g  = (const float*)d_in[8];
  const float* ln_b  = (const float*)d_in[9];
  const float* qkv_w = (const float*)d_in[10];
  const float* qkv_b = (const float*)d_in[11];
  const float* at_w  = (const float*)d_in[12];
  const float* at_b  = (const float*)d_in[13];
  const float* rpb   = (const float*)d_in[14];
  const float* w1    = (const float*)d_in[15];
  const float* b1    = (const float*)d_in[16];
  const float* g1g   = (const float*)d_in[17];
  const float* g1b   = (const float*)d_in[18];
  const float* w2    = (const float*)d_in[19];
  const float* b2    = (const float*)d_in[20];
  const float* g2g   = (const float*)d_in[21];
  const float* g2b   = (const float*)d_in[22];
  const float* recw  = (const float*)d_in[23];
  const float* recb  = (const float*)d_in[24];
  const int*   sidx  = (const int*)d_in[25];
  float* out = (float*)d_out;

  char* ws = (char*)d_ws;
  unsigned* Xg = (unsigned*)ws;
  float* f1    = (float*)(ws + 25165824);
  short* Qg    = (short*)(ws + 25165824);
  short* Kg    = (short*)(ws + 50331648);
  short* Vg    = (short*)(ws + 75497472);
  short* XtA   = (short*)(ws + 25165824);
  float* Y     = (float*)(ws + 50331648);
  int*   T     = (int*)(ws + 100663296);
  float* stats = (float*)(ws + 100665344);
  short* Wrec  = (short*)(ws + 100666368);

  char* dob = (char*)d_out;
  short* Og   = (short*)d_out;
  short* Wenc = (short*)(dob + 25165824);
  short* Wpe  = (short*)(dob + 25184256);
  short* Wqkv = (short*)(dob + 65937408);
  short* Waw  = (short*)(dob + 65992704);
  float* Bt   = (float*)(dob + 66011136);
  short* Wt1  = (short*)(dob + 66060288);
  short* Wt2  = (short*)(dob + 66557952);

  k_tables<<<1, 96, 0, stream>>>(sidx, T);
  k_wcv<<<972, 256, 0, stream>>>(w1, Wt1);
  k_wcv<<<972, 256, 0, stream>>>(w2, Wt2);
  k_cvt<<<108, 256, 0, stream>>>(qkv_w, Wqkv, 27648);
  k_cvt<<<36, 256, 0, stream>>>(at_w, Waw, 9216);
  k_cvt<<<36, 256, 0, stream>>>(enc_w, Wenc, 9216);
  k_cvt<<<24, 256, 0, stream>>>(pe_w, Wpe, 6144);
  k_wrt<<<48, 256, 0, stream>>>(recw, Wrec);
  k_bias<<<48, 256, 0, stream>>>(rpb, Bt);

  k_pe<<<1536, 256, 0, stream>>>(sp, Wpe, pe_b, pe_g, pe_be, f1);
  k_ie<<<2048, 256, 0, stream>>>(f1, ef, Wenc, enc_b, T, Xg);
  k_qkv<<<2048, 512, 0, stream>>>(Xg, Wqkv, qkv_b, ln_g, ln_b, Qg, Kg, Vg);
  k_att2<<<1536, 256, 0, stream>>>(Qg, Kg, Vg, Bt, Og);
  k_proj<<<2048, 256, 0, stream>>>(Og, Xg, Waw, at_b, XtA);

  hipMemsetAsync(stats, 0, 64 * sizeof(float), stream);
  k_convM<<<256, 512, 0, stream>>>(XtA, Wt1, b1, Y, stats);
  k_gn<<<6144, 256, 0, stream>>>(Y, stats, g1g, g1b, XtA);

  hipMemsetAsync(stats, 0, 64 * sizeof(float), stream);
  k_convM<<<256, 512, 0, stream>>>(XtA, Wt2, b2, Y, stats);
  k_gn<<<6144, 256, 0, stream>>>(Y, stats, g2g, g2b, XtA);

  k_final<<<4096, 256, 0, stream>>>(XtA, sp, Wrec, recb, T, out);
}